// Round 3
// baseline (2606.678 us; speedup 1.0000x reference)
//
#include <hip/hip_runtime.h>
#include <math.h>

#define NN 50000
#define NE 400000
#define CD 128
#define EPB 64          // edges per block in edge_kernel

typedef __attribute__((ext_vector_type(8))) short bf16x8;
typedef __attribute__((ext_vector_type(4))) float f32x4;

__device__ __forceinline__ float silu_f(float z) {
    return z / (1.f + __expf(-z));
}
__device__ __forceinline__ unsigned short f2bf(float x) {
    unsigned int u = __float_as_uint(x);
    u = (u + 0x7FFFu + ((u >> 16) & 1u)) >> 16;
    return (unsigned short)u;
}
__device__ __forceinline__ float bf2f(unsigned short h) {
    return __uint_as_float(((unsigned int)h) << 16);
}

// ---------------------------------------------------------------------------
// Wbig swizzle prep: Wbig[k][n], k in [0,320), n in [0,512)
//   k<256:  n<256 -> Wn1l[k][n], else Wc1l[k][n-256]
//   k>=256: Aep fold: sum_j We2l[k-256][j] * W1[(256+j)][n']
// Stored in MFMA B-frag lane order: [layer][ntile(32)][kstep(10)][lane(64)][j(8)]
// ---------------------------------------------------------------------------
__global__ __launch_bounds__(64) void wbig_prep(
        const float* __restrict__ We2, const float* __restrict__ Wn1,
        const float* __restrict__ Wc1, unsigned short* __restrict__ wbig)
{
    const int l = blockIdx.y;
    const int ntile = blockIdx.x / 10;
    const int ks = blockIdx.x % 10;
    const int lane = threadIdx.x;
    const int n = ntile * 16 + (lane & 15);
    const int kbase = ks * 32 + (lane >> 4) * 8;
    const float* Wn1l = Wn1 + (size_t)l * 320 * 256;
    const float* Wc1l = Wc1 + (size_t)l * 320 * 256;
    const float* We2l = We2 + (size_t)l * 64 * 64;
    const float* W1 = (n < 256) ? Wn1l : Wc1l;
    const int nn = n & 255;
    unsigned short* outp = wbig + ((((size_t)l * 32 + ntile) * 10 + ks) * 64 + lane) * 8;
    #pragma unroll
    for (int j = 0; j < 8; ++j) {
        int k = kbase + j;
        float val;
        if (k < 256) {
            val = W1[(size_t)k * 256 + nn];
        } else {
            int i = k - 256;
            float acc = 0.f;
            #pragma unroll 8
            for (int jj = 0; jj < 64; ++jj)
                acc += We2l[i * 64 + jj] * W1[(size_t)(256 + jj) * 256 + nn];
            val = acc;
        }
        outp[j] = f2bf(val);
    }
}

// ---------------------------------------------------------------------------
// Wn2 swizzle: B[k][n] = Wn2l[k][n], k in [0,256), n in [0,128)
// [layer][ntile(8)][kstep(8)][lane(64)][j(8)]
// ---------------------------------------------------------------------------
__global__ __launch_bounds__(64) void wn2_prep(
        const float* __restrict__ Wn2, unsigned short* __restrict__ wn2s)
{
    const int l = blockIdx.y;
    const int ntile = blockIdx.x / 8;
    const int ks = blockIdx.x % 8;
    const int lane = threadIdx.x;
    const int n = ntile * 16 + (lane & 15);
    const int kbase = ks * 32 + (lane >> 4) * 8;
    const float* Wn2l = Wn2 + (size_t)l * 256 * 128;
    unsigned short* outp = wn2s + ((((size_t)l * 8 + ntile) * 8 + ks) * 64 + lane) * 8;
    #pragma unroll
    for (int j = 0; j < 8; ++j)
        outp[j] = f2bf(Wn2l[(size_t)(kbase + j) * 128 + n]);
}

// ---------------------------------------------------------------------------
// cep[l][n] = sum_j be2[j]*W1[(256+j)][n'] + bias1[n']   (fp32)
// ---------------------------------------------------------------------------
__global__ __launch_bounds__(512) void cep_prep(
        const float* __restrict__ be2,
        const float* __restrict__ Wn1, const float* __restrict__ Wc1,
        const float* __restrict__ bn1, const float* __restrict__ bc1,
        float* __restrict__ cep)
{
    const int l = blockIdx.x;
    const int j = threadIdx.x;
    const int jj = j & 255;
    const float* W1 = ((j < 256) ? Wn1 : Wc1) + (size_t)l * 320 * 256;
    const float* be2l = be2 + l * 64;
    float acc = (j < 256) ? bn1[l * 256 + jj] : bc1[l * 256 + jj];
    #pragma unroll 8
    for (int k = 0; k < 64; ++k)
        acc += be2l[k] * W1[(size_t)(256 + k) * 256 + jj];
    cep[l * 512 + j] = acc;
}

// ---------------------------------------------------------------------------
// fp32 -> bf16 convert (h shadow), 4 elems/thread
// ---------------------------------------------------------------------------
__global__ __launch_bounds__(256) void conv_kernel(
        const float* __restrict__ h, unsigned short* __restrict__ hbf)
{
    const int i = (blockIdx.x * 256 + threadIdx.x) * 4;
    float4 v = *(const float4*)(h + i);
    ushort4 o;
    o.x = f2bf(v.x); o.y = f2bf(v.y); o.z = f2bf(v.z); o.w = f2bf(v.w);
    *(ushort4*)(hbf + i) = o;
}

// ---------------------------------------------------------------------------
// Fused edge kernel, MFMA. 64 edges/block, 1024 threads (16 waves).
// GEMM1: A=[hbf[src]|hbf[dst]|s] (64x320) @ Wbig (320x512) -> silu -> t (LDS)
//   wave w owns ntiles {2w, 2w+1} (cols 32w..32w+31), all 4 mtiles.
// GEMM2: t[:,0:256] @ Wn2 (256x128) -> + bn2 -> atomic h[dst] (in place)
//   wave w owns coltile w>>1, mtiles {(w&1)*2, (w&1)*2+1}.
// coord: dot(t[:,256:512], Wc2) -> atomic x_out[dst] += cw*(x[src]-x[dst])
// ---------------------------------------------------------------------------
__global__ __launch_bounds__(1024) void edge_kernel(
        const int* __restrict__ eidx, const float* __restrict__ edist,
        const float* __restrict__ We1l, const float* __restrict__ be1l,
        const unsigned short* __restrict__ hbf,
        const unsigned short* __restrict__ wbig_l,
        const unsigned short* __restrict__ wn2_l,
        const float* __restrict__ cep_l, const float* __restrict__ bn2l,
        const float* __restrict__ Wc2l,
        const float* __restrict__ x_in,
        float* __restrict__ h_glob, float* __restrict__ x_out)
{
    __shared__ __align__(16) unsigned short s_s[EPB][72];   // s bf16 (64 + 8 pad)
    __shared__ __align__(16) unsigned short s_t[EPB][520];  // t bf16 (512 + 8 pad)
    __shared__ int s_src[EPB], s_dst[EPB];
    __shared__ float s_wc2[256];

    const int tid = threadIdx.x;
    const int eb = blockIdx.x * EPB;

    if (tid < EPB) {
        s_src[tid] = eidx[eb + tid];
        s_dst[tid] = eidx[NE + eb + tid];
    }
    if (tid < 256) s_wc2[tid] = Wc2l[tid];
    {   // s = silu(d * We1 + be1), 4 elems/thread (1024 threads, 64x64 vals)
        const int e = tid >> 4;
        const int j0 = (tid & 15) * 4;
        const float d = edist[eb + e];
        unsigned short tmp[4];
        #pragma unroll
        for (int j = 0; j < 4; ++j)
            tmp[j] = f2bf(silu_f(d * We1l[j0 + j] + be1l[j0 + j]));
        *(uint2*)&s_s[e][j0] = *(const uint2*)tmp;
    }
    __syncthreads();

    const int wave = tid >> 6, lane = tid & 63;
    const int m = lane & 15, q = lane >> 4;

    int srcs[4], dsts[4];
    #pragma unroll
    for (int mt = 0; mt < 4; ++mt) {
        srcs[mt] = s_src[mt * 16 + m];
        dsts[mt] = s_dst[mt * 16 + m];
    }

    // ---- GEMM1 ----
    f32x4 acc[2][4];   // [nt][mt]
    #pragma unroll
    for (int nt = 0; nt < 2; ++nt)
        #pragma unroll
        for (int mt = 0; mt < 4; ++mt)
            acc[nt][mt] = (f32x4){0.f, 0.f, 0.f, 0.f};

    #pragma unroll
    for (int ks = 0; ks < 10; ++ks) {
        const int koff = ks * 32 + q * 8;
        bf16x8 a[4];
        if (ks < 4) {
            #pragma unroll
            for (int mt = 0; mt < 4; ++mt)
                a[mt] = *(const bf16x8*)(hbf + (size_t)srcs[mt] * CD + koff);
        } else if (ks < 8) {
            #pragma unroll
            for (int mt = 0; mt < 4; ++mt)
                a[mt] = *(const bf16x8*)(hbf + (size_t)dsts[mt] * CD + (koff - 128));
        } else {
            #pragma unroll
            for (int mt = 0; mt < 4; ++mt)
                a[mt] = *(const bf16x8*)&s_s[mt * 16 + m][koff - 256];
        }
        #pragma unroll
        for (int nt = 0; nt < 2; ++nt) {
            bf16x8 b = *(const bf16x8*)(wbig_l +
                ((size_t)((wave * 2 + nt) * 10 + ks) * 64 + lane) * 8);
            #pragma unroll
            for (int mt = 0; mt < 4; ++mt)
                acc[nt][mt] = __builtin_amdgcn_mfma_f32_16x16x32_bf16(a[mt], b, acc[nt][mt], 0, 0, 0);
        }
    }
    // epilogue: + cep, silu, bf16 -> s_t
    #pragma unroll
    for (int nt = 0; nt < 2; ++nt) {
        const int col = (wave * 2 + nt) * 16 + m;
        const float c = cep_l[col];
        #pragma unroll
        for (int mt = 0; mt < 4; ++mt) {
            #pragma unroll
            for (int i = 0; i < 4; ++i) {
                float tv = silu_f(acc[nt][mt][i] + c);
                s_t[mt * 16 + q * 4 + i][col] = f2bf(tv);
            }
        }
    }
    __syncthreads();

    // ---- GEMM2 ----
    {
        const int ct = wave >> 1;            // col tile 0..7
        const int mbase = (wave & 1) * 2;    // mtiles {mbase, mbase+1}
        f32x4 acc2[2];
        acc2[0] = (f32x4){0.f, 0.f, 0.f, 0.f};
        acc2[1] = (f32x4){0.f, 0.f, 0.f, 0.f};
        #pragma unroll
        for (int ks = 0; ks < 8; ++ks) {
            bf16x8 a0 = *(const bf16x8*)&s_t[mbase * 16 + m][ks * 32 + q * 8];
            bf16x8 a1 = *(const bf16x8*)&s_t[(mbase + 1) * 16 + m][ks * 32 + q * 8];
            bf16x8 b = *(const bf16x8*)(wn2_l + ((size_t)(ct * 8 + ks) * 64 + lane) * 8);
            acc2[0] = __builtin_amdgcn_mfma_f32_16x16x32_bf16(a0, b, acc2[0], 0, 0, 0);
            acc2[1] = __builtin_amdgcn_mfma_f32_16x16x32_bf16(a1, b, acc2[1], 0, 0, 0);
        }
        const int col = ct * 16 + m;
        const float bb = bn2l[col];
        #pragma unroll
        for (int u = 0; u < 2; ++u) {
            #pragma unroll
            for (int i = 0; i < 4; ++i) {
                const int e = (mbase + u) * 16 + q * 4 + i;
                atomicAdd(&h_glob[(size_t)s_dst[e] * CD + col], acc2[u][i] + bb);
            }
        }
    }

    // ---- coord path: 16 threads per edge ----
    {
        const int e = tid >> 4, r = tid & 15;
        float sum = 0.f;
        #pragma unroll 4
        for (int k = r; k < 256; k += 16)
            sum += bf2f(s_t[e][256 + k]) * s_wc2[k];
        sum += __shfl_xor(sum, 1);
        sum += __shfl_xor(sum, 2);
        sum += __shfl_xor(sum, 4);
        sum += __shfl_xor(sum, 8);
        if (r == 0) {
            const int sn = s_src[e], dn = s_dst[e];
            float dx0 = x_in[sn * 3 + 0] - x_in[dn * 3 + 0];
            float dx1 = x_in[sn * 3 + 1] - x_in[dn * 3 + 1];
            float dx2 = x_in[sn * 3 + 2] - x_in[dn * 3 + 2];
            atomicAdd(&x_out[dn * 3 + 0], sum * dx0);
            atomicAdd(&x_out[dn * 3 + 1], sum * dx1);
            atomicAdd(&x_out[dn * 3 + 2], sum * dx2);
        }
    }
}

// ---------------------------------------------------------------------------
// Final LayerNorm over C=128 + copy x.
// ---------------------------------------------------------------------------
__global__ __launch_bounds__(256) void final_kernel(
        const float* __restrict__ h, const float* __restrict__ x,
        const float* __restrict__ gamma, const float* __restrict__ beta,
        float* __restrict__ out)
{
    const int lane = threadIdx.x & 63;
    const int wave = threadIdx.x >> 6;
    const int n = blockIdx.x * 4 + wave;
    float v0 = h[(size_t)n * CD + lane];
    float v1 = h[(size_t)n * CD + 64 + lane];
    float ssum = v0 + v1;
    for (int off = 32; off; off >>= 1) ssum += __shfl_xor(ssum, off);
    float mu = ssum * (1.f / 128.f);
    float d0 = v0 - mu, d1 = v1 - mu;
    float sq = d0 * d0 + d1 * d1;
    for (int off = 32; off; off >>= 1) sq += __shfl_xor(sq, off);
    float rstd = rsqrtf(sq * (1.f / 128.f) + 1e-5f);
    out[(size_t)n * CD + lane]      = gamma[lane]      * d0 * rstd + beta[lane];
    out[(size_t)n * CD + 64 + lane] = gamma[64 + lane] * d1 * rstd + beta[64 + lane];
    if (threadIdx.x < 12) {
        int nn = blockIdx.x * 4 + threadIdx.x / 3;
        int c = threadIdx.x % 3;
        out[(size_t)NN * CD + nn * 3 + c] = x[nn * 3 + c];
    }
}

static inline size_t align_up(size_t v) { return (v + 255) & ~(size_t)255; }

extern "C" void kernel_launch(void* const* d_in, const int* in_sizes, int n_in,
                              void* d_out, int out_size, void* d_ws, size_t ws_size,
                              hipStream_t stream)
{
    const float* single = (const float*)d_in[0];
    const float* coords = (const float*)d_in[2];
    const int*   eidx   = (const int*)d_in[3];
    const float* edist  = (const float*)d_in[4];
    const float* We1 = (const float*)d_in[5];
    const float* be1 = (const float*)d_in[6];
    const float* We2 = (const float*)d_in[7];
    const float* be2 = (const float*)d_in[8];
    const float* Wn1 = (const float*)d_in[9];
    const float* bn1 = (const float*)d_in[10];
    const float* Wn2 = (const float*)d_in[11];
    const float* bn2 = (const float*)d_in[12];
    const float* Wc1 = (const float*)d_in[13];
    const float* bc1 = (const float*)d_in[14];
    const float* Wc2 = (const float*)d_in[15];
    const float* gamma = (const float*)d_in[16];
    const float* beta  = (const float*)d_in[17];
    float* out = (float*)d_out;

    char* w = (char*)d_ws;
    float* h0  = (float*)w;  w += align_up((size_t)NN * CD * 4);
    float* x0  = (float*)w;  w += align_up((size_t)NN * 3 * 4);
    float* x1  = (float*)w;  w += align_up((size_t)NN * 3 * 4);
    unsigned short* hbf  = (unsigned short*)w; w += align_up((size_t)NN * CD * 2);
    unsigned short* wbig = (unsigned short*)w; w += align_up((size_t)4 * 512 * 320 * 2);
    unsigned short* wn2s = (unsigned short*)w; w += align_up((size_t)4 * 256 * 128 * 2);
    float* cep = (float*)w;  w += align_up((size_t)4 * 512 * 4);

    wbig_prep<<<dim3(320, 4), 64, 0, stream>>>(We2, Wn1, Wc1, wbig);
    wn2_prep<<<dim3(64, 4), 64, 0, stream>>>(Wn2, wn2s);
    cep_prep<<<4, 512, 0, stream>>>(be2, Wn1, Wc1, bn1, bc1, cep);

    hipMemcpyAsync(h0, single, (size_t)NN * CD * 4, hipMemcpyDeviceToDevice, stream);
    hipMemcpyAsync(x0, coords, (size_t)NN * 3 * 4, hipMemcpyDeviceToDevice, stream);

    float* xc = x0; float* xn = x1;
    for (int l = 0; l < 4; ++l) {
        conv_kernel<<<(NN * CD) / 1024, 256, 0, stream>>>(h0, hbf);
        hipMemcpyAsync(xn, xc, (size_t)NN * 3 * 4, hipMemcpyDeviceToDevice, stream);
        edge_kernel<<<NE / EPB, 1024, 0, stream>>>(
            eidx, edist,
            We1 + l * 64, be1 + l * 64,
            hbf,
            wbig + (size_t)l * 512 * 320,
            wn2s + (size_t)l * 256 * 128,
            cep + l * 512, bn2 + l * CD, Wc2 + l * 256,
            xc, h0, xn);
        float* t = xc; xc = xn; xn = t;
    }
    final_kernel<<<NN / 4, 256, 0, stream>>>(h0, xc, gamma, beta, out);
}

// Round 4
// 1791.730 us; speedup vs baseline: 1.4548x; 1.4548x over previous
//
#include <hip/hip_runtime.h>
#include <math.h>

#define NN 50000
#define NE 400000
#define CD 128
#define EPB 64          // edges per block in edge_kernel
#define HBINS 50176     // 196*256, >= NN

typedef __attribute__((ext_vector_type(8))) short bf16x8;
typedef __attribute__((ext_vector_type(4))) float f32x4;

__device__ __forceinline__ float silu_f(float z) {
    return z / (1.f + __expf(-z));
}
__device__ __forceinline__ unsigned short f2bf(float x) {
    unsigned int u = __float_as_uint(x);
    u = (u + 0x7FFFu + ((u >> 16) & 1u)) >> 16;
    return (unsigned short)u;
}
__device__ __forceinline__ float bf2f(unsigned short h) {
    return __uint_as_float(((unsigned int)h) << 16);
}

// ======================= edge sort by dst (counting sort) ===================
__global__ __launch_bounds__(256) void hist_kernel(
        const int* __restrict__ dst, int* __restrict__ hist)
{
    int e = blockIdx.x * 256 + threadIdx.x;
    if (e < NE) atomicAdd(&hist[dst[e]], 1);
}

__global__ __launch_bounds__(256) void scan1_kernel(
        const int* __restrict__ hist, int* __restrict__ offs, int* __restrict__ bsum)
{
    __shared__ int sh[256];
    const int t = threadIdx.x;
    const int i = blockIdx.x * 256 + t;
    int v = hist[i];
    sh[t] = v;
    __syncthreads();
    for (int off = 1; off < 256; off <<= 1) {
        int x = (t >= off) ? sh[t - off] : 0;
        __syncthreads();
        sh[t] += x;
        __syncthreads();
    }
    offs[i] = sh[t] - v;                 // exclusive
    if (t == 255) bsum[blockIdx.x] = sh[t];
}

__global__ __launch_bounds__(256) void scan2_kernel(int* __restrict__ bsum)
{
    __shared__ int sh[256];
    const int t = threadIdx.x;
    int v = (t < 196) ? bsum[t] : 0;
    sh[t] = v;
    __syncthreads();
    for (int off = 1; off < 256; off <<= 1) {
        int x = (t >= off) ? sh[t - off] : 0;
        __syncthreads();
        sh[t] += x;
        __syncthreads();
    }
    if (t < 196) bsum[t] = sh[t] - v;    // exclusive
}

__global__ __launch_bounds__(256) void scan3_kernel(
        const int* __restrict__ offs, const int* __restrict__ bsum,
        int* __restrict__ cursor)
{
    const int i = blockIdx.x * 256 + threadIdx.x;
    cursor[i] = offs[i] + bsum[blockIdx.x];
}

__global__ __launch_bounds__(256) void scatter_kernel(
        const int* __restrict__ eidx, const float* __restrict__ edist,
        int* __restrict__ cursor,
        int* __restrict__ ssrc, int* __restrict__ sdst, float* __restrict__ sdist)
{
    int e = blockIdx.x * 256 + threadIdx.x;
    if (e < NE) {
        int d = eidx[NE + e];
        int p = atomicAdd(&cursor[d], 1);
        ssrc[p] = eidx[e];
        sdst[p] = d;
        sdist[p] = edist[e];
    }
}

// ======================= weight prep (unchanged math) =======================
__global__ __launch_bounds__(64) void wbig_prep(
        const float* __restrict__ We2, const float* __restrict__ Wn1,
        const float* __restrict__ Wc1, unsigned short* __restrict__ wbig)
{
    const int l = blockIdx.y;
    const int ntile = blockIdx.x / 10;
    const int ks = blockIdx.x % 10;
    const int lane = threadIdx.x;
    const int n = ntile * 16 + (lane & 15);
    const int kbase = ks * 32 + (lane >> 4) * 8;
    const float* Wn1l = Wn1 + (size_t)l * 320 * 256;
    const float* Wc1l = Wc1 + (size_t)l * 320 * 256;
    const float* We2l = We2 + (size_t)l * 64 * 64;
    const float* W1 = (n < 256) ? Wn1l : Wc1l;
    const int nn = n & 255;
    unsigned short* outp = wbig + ((((size_t)l * 32 + ntile) * 10 + ks) * 64 + lane) * 8;
    #pragma unroll
    for (int j = 0; j < 8; ++j) {
        int k = kbase + j;
        float val;
        if (k < 256) {
            val = W1[(size_t)k * 256 + nn];
        } else {
            int i = k - 256;
            float acc = 0.f;
            #pragma unroll 8
            for (int jj = 0; jj < 64; ++jj)
                acc += We2l[i * 64 + jj] * W1[(size_t)(256 + jj) * 256 + nn];
            val = acc;
        }
        outp[j] = f2bf(val);
    }
}

__global__ __launch_bounds__(64) void wn2_prep(
        const float* __restrict__ Wn2, unsigned short* __restrict__ wn2s)
{
    const int l = blockIdx.y;
    const int ntile = blockIdx.x / 8;
    const int ks = blockIdx.x % 8;
    const int lane = threadIdx.x;
    const int n = ntile * 16 + (lane & 15);
    const int kbase = ks * 32 + (lane >> 4) * 8;
    const float* Wn2l = Wn2 + (size_t)l * 256 * 128;
    unsigned short* outp = wn2s + ((((size_t)l * 8 + ntile) * 8 + ks) * 64 + lane) * 8;
    #pragma unroll
    for (int j = 0; j < 8; ++j)
        outp[j] = f2bf(Wn2l[(size_t)(kbase + j) * 128 + n]);
}

__global__ __launch_bounds__(512) void cep_prep(
        const float* __restrict__ be2,
        const float* __restrict__ Wn1, const float* __restrict__ Wc1,
        const float* __restrict__ bn1, const float* __restrict__ bc1,
        float* __restrict__ cep)
{
    const int l = blockIdx.x;
    const int j = threadIdx.x;
    const int jj = j & 255;
    const float* W1 = ((j < 256) ? Wn1 : Wc1) + (size_t)l * 320 * 256;
    const float* be2l = be2 + l * 64;
    float acc = (j < 256) ? bn1[l * 256 + jj] : bc1[l * 256 + jj];
    #pragma unroll 8
    for (int k = 0; k < 64; ++k)
        acc += be2l[k] * W1[(size_t)(256 + k) * 256 + jj];
    cep[l * 512 + j] = acc;
}

__global__ __launch_bounds__(256) void conv_kernel(
        const float* __restrict__ h, unsigned short* __restrict__ hbf)
{
    const int i = (blockIdx.x * 256 + threadIdx.x) * 4;
    float4 v = *(const float4*)(h + i);
    ushort4 o;
    o.x = f2bf(v.x); o.y = f2bf(v.y); o.z = f2bf(v.z); o.w = f2bf(v.w);
    *(ushort4*)(hbf + i) = o;
}

// ======================= fused edge kernel (sorted edges) ===================
// 64 edges/block, 1024 threads (16 waves).
// Phase 0: stage [hbf[src]|hbf[dst]|s] rows into LDS s_A (padded stride 328).
// GEMM1: wave w: ntiles {2w,2w+1}, all 4 mtiles; A from LDS; B from global.
// GEMM2: wave w: coltile w>>1, mtiles {(w&1)*2,(w&1)*2+1}; result -> t_h (LDS,
//        aliasing s_t cols 0..255 region as fp32).
// Segsum: edges sorted by dst -> run-sum over equal dst, one atomic per run/col.
// Coord: per-edge dot + per-edge x atomics (dst-clustered -> L1/L2-local).
// ---------------------------------------------------------------------------
__global__ __launch_bounds__(1024) void edge_kernel(
        const int* __restrict__ ssrc, const int* __restrict__ sdst,
        const float* __restrict__ sdist,
        const float* __restrict__ We1l, const float* __restrict__ be1l,
        const unsigned short* __restrict__ hbf,
        const unsigned short* __restrict__ wbig_l,
        const unsigned short* __restrict__ wn2_l,
        const float* __restrict__ cep_l, const float* __restrict__ bn2l,
        const float* __restrict__ Wc2l,
        const float* __restrict__ x_in,
        float* __restrict__ h_glob, float* __restrict__ x_out)
{
    __shared__ __align__(16) unsigned short s_A[EPB][328];  // 320 + 8 pad
    __shared__ __align__(16) unsigned short s_t[EPB][520];  // 512 + 8 pad
    __shared__ int s_src[EPB], s_dst[EPB];
    __shared__ unsigned char s_flag[EPB];
    __shared__ float s_wc2[256];

    const int tid = threadIdx.x;
    const int eb = blockIdx.x * EPB;

    if (tid < EPB) {
        int sv = ssrc[eb + tid], dv = sdst[eb + tid];
        s_src[tid] = sv;
        s_dst[tid] = dv;
        // run-end flags (single wave: LDS write->read ordered within wave)
        s_flag[tid] = (tid == EPB - 1) ? 1 : (unsigned char)(dv != sdst[eb + tid + 1]);
    }
    if (tid < 256) s_wc2[tid] = Wc2l[tid];
    {   // s = silu(d*We1+be1) -> s_A[e][256..319]
        const int e = tid >> 4;
        const int j0 = (tid & 15) * 4;
        const float d = sdist[eb + e];
        unsigned short tmp[4];
        #pragma unroll
        for (int j = 0; j < 4; ++j)
            tmp[j] = f2bf(silu_f(d * We1l[j0 + j] + be1l[j0 + j]));
        *(uint2*)&s_A[e][256 + j0] = *(const uint2*)tmp;
    }
    __syncthreads();   // s_src/s_dst ready for staging

    // ---- stage h rows: 2048 chunks of 16B ----
    #pragma unroll
    for (int c = tid; c < 2048; c += 1024) {
        const int row = c >> 5, ch = c & 31;
        const int node = (ch < 16) ? s_src[row] : s_dst[row];
        const int koff = (ch & 15) * 8;
        bf16x8 v = *(const bf16x8*)(hbf + (size_t)node * CD + koff);
        *(bf16x8*)&s_A[row][ch * 8] = v;
    }
    __syncthreads();

    const int wave = tid >> 6, lane = tid & 63;
    const int m = lane & 15, q = lane >> 4;

    // ---- GEMM1 ----
    f32x4 acc[2][4];   // [nt][mt]
    #pragma unroll
    for (int nt = 0; nt < 2; ++nt)
        #pragma unroll
        for (int mt = 0; mt < 4; ++mt)
            acc[nt][mt] = (f32x4){0.f, 0.f, 0.f, 0.f};

    #pragma unroll
    for (int ks = 0; ks < 10; ++ks) {
        const int koff = ks * 32 + q * 8;
        bf16x8 a[4];
        #pragma unroll
        for (int mt = 0; mt < 4; ++mt)
            a[mt] = *(const bf16x8*)&s_A[mt * 16 + m][koff];
        #pragma unroll
        for (int nt = 0; nt < 2; ++nt) {
            bf16x8 b = *(const bf16x8*)(wbig_l +
                ((size_t)((wave * 2 + nt) * 10 + ks) * 64 + lane) * 8);
            #pragma unroll
            for (int mt = 0; mt < 4; ++mt)
                acc[nt][mt] = __builtin_amdgcn_mfma_f32_16x16x32_bf16(a[mt], b, acc[nt][mt], 0, 0, 0);
        }
    }
    // epilogue: + cep, silu, bf16 -> s_t
    #pragma unroll
    for (int nt = 0; nt < 2; ++nt) {
        const int col = (wave * 2 + nt) * 16 + m;
        const float c = cep_l[col];
        #pragma unroll
        for (int mt = 0; mt < 4; ++mt) {
            #pragma unroll
            for (int i = 0; i < 4; ++i) {
                float tv = silu_f(acc[nt][mt][i] + c);
                s_t[mt * 16 + q * 4 + i][col] = f2bf(tv);
            }
        }
    }
    __syncthreads();

    // ---- GEMM2 ----
    f32x4 acc2[2];
    acc2[0] = (f32x4){0.f, 0.f, 0.f, 0.f};
    acc2[1] = (f32x4){0.f, 0.f, 0.f, 0.f};
    const int ct = wave >> 1;            // col tile 0..7
    const int mbase = (wave & 1) * 2;    // mtiles {mbase, mbase+1}
    #pragma unroll
    for (int ks = 0; ks < 8; ++ks) {
        bf16x8 a0 = *(const bf16x8*)&s_t[mbase * 16 + m][ks * 32 + q * 8];
        bf16x8 a1 = *(const bf16x8*)&s_t[(mbase + 1) * 16 + m][ks * 32 + q * 8];
        bf16x8 b = *(const bf16x8*)(wn2_l + ((size_t)(ct * 8 + ks) * 64 + lane) * 8);
        acc2[0] = __builtin_amdgcn_mfma_f32_16x16x32_bf16(a0, b, acc2[0], 0, 0, 0);
        acc2[1] = __builtin_amdgcn_mfma_f32_16x16x32_bf16(a1, b, acc2[1], 0, 0, 0);
    }
    __syncthreads();   // all GEMM2 reads of s_t[.., 0:256] done

    // write m into t_h (fp32, aliases s_t bytes [0,512) of each row)
    {
        const int col = ct * 16 + m;
        const float bb = bn2l[col];
        #pragma unroll
        for (int u = 0; u < 2; ++u) {
            #pragma unroll
            for (int i = 0; i < 4; ++i) {
                const int e = (mbase + u) * 16 + q * 4 + i;
                float* th = (float*)((char*)&s_t[0][0] + (size_t)e * 1040);
                th[col] = acc2[u][i] + bb;
            }
        }
    }
    __syncthreads();

    // ---- coord path: 16 threads per edge (reads s_t cols 256..511) ----
    {
        const int e = tid >> 4, r = tid & 15;
        float sum = 0.f;
        #pragma unroll 4
        for (int k = r; k < 256; k += 16)
            sum += bf2f(s_t[e][256 + k]) * s_wc2[k];
        sum += __shfl_xor(sum, 1);
        sum += __shfl_xor(sum, 2);
        sum += __shfl_xor(sum, 4);
        sum += __shfl_xor(sum, 8);
        if (r == 0) {
            const int sn = s_src[e], dn = s_dst[e];
            float dx0 = x_in[sn * 3 + 0] - x_in[dn * 3 + 0];
            float dx1 = x_in[sn * 3 + 1] - x_in[dn * 3 + 1];
            float dx2 = x_in[sn * 3 + 2] - x_in[dn * 3 + 2];
            atomicAdd(&x_out[dn * 3 + 0], sum * dx0);
            atomicAdd(&x_out[dn * 3 + 1], sum * dx1);
            atomicAdd(&x_out[dn * 3 + 2], sum * dx2);
        }
    }

    // ---- segmented h reduction: 128 threads, runs of equal dst ----
    if (tid < 128) {
        const int col = tid;
        float val = 0.f;
        #pragma unroll 4
        for (int e = 0; e < EPB; ++e) {
            const float* th = (const float*)((const char*)&s_t[0][0] + (size_t)e * 1040);
            val += th[col];
            if (s_flag[e]) {
                atomicAdd(&h_glob[(size_t)s_dst[e] * CD + col], val);
                val = 0.f;
            }
        }
    }
}

// ======================= final layernorm ====================================
__global__ __launch_bounds__(256) void final_kernel(
        const float* __restrict__ h, const float* __restrict__ x,
        const float* __restrict__ gamma, const float* __restrict__ beta,
        float* __restrict__ out)
{
    const int lane = threadIdx.x & 63;
    const int wave = threadIdx.x >> 6;
    const int n = blockIdx.x * 4 + wave;
    float v0 = h[(size_t)n * CD + lane];
    float v1 = h[(size_t)n * CD + 64 + lane];
    float ssum = v0 + v1;
    for (int off = 32; off; off >>= 1) ssum += __shfl_xor(ssum, off);
    float mu = ssum * (1.f / 128.f);
    float d0 = v0 - mu, d1 = v1 - mu;
    float sq = d0 * d0 + d1 * d1;
    for (int off = 32; off; off >>= 1) sq += __shfl_xor(sq, off);
    float rstd = rsqrtf(sq * (1.f / 128.f) + 1e-5f);
    out[(size_t)n * CD + lane]      = gamma[lane]      * d0 * rstd + beta[lane];
    out[(size_t)n * CD + 64 + lane] = gamma[64 + lane] * d1 * rstd + beta[64 + lane];
    if (threadIdx.x < 12) {
        int nn = blockIdx.x * 4 + threadIdx.x / 3;
        int c = threadIdx.x % 3;
        out[(size_t)NN * CD + nn * 3 + c] = x[nn * 3 + c];
    }
}

static inline size_t align_up(size_t v) { return (v + 255) & ~(size_t)255; }

extern "C" void kernel_launch(void* const* d_in, const int* in_sizes, int n_in,
                              void* d_out, int out_size, void* d_ws, size_t ws_size,
                              hipStream_t stream)
{
    const float* single = (const float*)d_in[0];
    const float* coords = (const float*)d_in[2];
    const int*   eidx   = (const int*)d_in[3];
    const float* edist  = (const float*)d_in[4];
    const float* We1 = (const float*)d_in[5];
    const float* be1 = (const float*)d_in[6];
    const float* We2 = (const float*)d_in[7];
    const float* be2 = (const float*)d_in[8];
    const float* Wn1 = (const float*)d_in[9];
    const float* bn1 = (const float*)d_in[10];
    const float* Wn2 = (const float*)d_in[11];
    const float* bn2 = (const float*)d_in[12];
    const float* Wc1 = (const float*)d_in[13];
    const float* bc1 = (const float*)d_in[14];
    const float* Wc2 = (const float*)d_in[15];
    const float* gamma = (const float*)d_in[16];
    const float* beta  = (const float*)d_in[17];
    float* out = (float*)d_out;

    char* w = (char*)d_ws;
    float* h0  = (float*)w;  w += align_up((size_t)NN * CD * 4);
    float* x0  = (float*)w;  w += align_up((size_t)NN * 3 * 4);
    float* x1  = (float*)w;  w += align_up((size_t)NN * 3 * 4);
    unsigned short* hbf  = (unsigned short*)w; w += align_up((size_t)NN * CD * 2);
    unsigned short* wbig = (unsigned short*)w; w += align_up((size_t)4 * 512 * 320 * 2);
    unsigned short* wn2s = (unsigned short*)w; w += align_up((size_t)4 * 256 * 128 * 2);
    float* cep = (float*)w;  w += align_up((size_t)4 * 512 * 4);
    int* hist   = (int*)w;   w += align_up((size_t)HBINS * 4);
    int* offs   = (int*)w;   w += align_up((size_t)HBINS * 4);
    int* cursor = (int*)w;   w += align_up((size_t)HBINS * 4);
    int* bsum   = (int*)w;   w += align_up((size_t)256 * 4);
    int* ssrc   = (int*)w;   w += align_up((size_t)NE * 4);
    int* sdst   = (int*)w;   w += align_up((size_t)NE * 4);
    float* sdist = (float*)w; w += align_up((size_t)NE * 4);

    // ---- sort edges by dst (once; constant across layers) ----
    hipMemsetAsync(hist, 0, (size_t)HBINS * 4, stream);
    hist_kernel<<<(NE + 255) / 256, 256, 0, stream>>>(eidx + NE, hist);
    scan1_kernel<<<HBINS / 256, 256, 0, stream>>>(hist, offs, bsum);
    scan2_kernel<<<1, 256, 0, stream>>>(bsum);
    scan3_kernel<<<HBINS / 256, 256, 0, stream>>>(offs, bsum, cursor);
    scatter_kernel<<<(NE + 255) / 256, 256, 0, stream>>>(eidx, edist, cursor, ssrc, sdst, sdist);

    // ---- weight prep ----
    wbig_prep<<<dim3(320, 4), 64, 0, stream>>>(We2, Wn1, Wc1, wbig);
    wn2_prep<<<dim3(64, 4), 64, 0, stream>>>(Wn2, wn2s);
    cep_prep<<<4, 512, 0, stream>>>(be2, Wn1, Wc1, bn1, bc1, cep);

    hipMemcpyAsync(h0, single, (size_t)NN * CD * 4, hipMemcpyDeviceToDevice, stream);
    hipMemcpyAsync(x0, coords, (size_t)NN * 3 * 4, hipMemcpyDeviceToDevice, stream);

    float* xc = x0; float* xn = x1;
    for (int l = 0; l < 4; ++l) {
        conv_kernel<<<(NN * CD) / 1024, 256, 0, stream>>>(h0, hbf);
        hipMemcpyAsync(xn, xc, (size_t)NN * 3 * 4, hipMemcpyDeviceToDevice, stream);
        edge_kernel<<<NE / EPB, 1024, 0, stream>>>(
            ssrc, sdst, sdist,
            We1 + l * 64, be1 + l * 64,
            hbf,
            wbig + (size_t)l * 512 * 320,
            wn2s + (size_t)l * 256 * 128,
            cep + l * 512, bn2 + l * CD, Wc2 + l * 256,
            xc, h0, xn);
        float* t = xc; xc = xn; xn = t;
    }
    final_kernel<<<NN / 4, 256, 0, stream>>>(h0, xc, gamma, beta, out);
}

// Round 5
// 1686.928 us; speedup vs baseline: 1.5452x; 1.0621x over previous
//
#include <hip/hip_runtime.h>
#include <hip/hip_bf16.h>
#include <math.h>

#define NN 50000
#define NE 400000
#define CD 128
#define EPB 64          // edges per block in edge_kernel
#define HBINS 50176     // 196*256, >= NN

typedef __attribute__((ext_vector_type(8))) short bf16x8;
typedef __attribute__((ext_vector_type(4))) float f32x4;

__device__ __forceinline__ float silu_f(float z) {
    // z / (1+e^-z) with hardware v_rcp_f32 (~1 ulp; invisible vs bf16 rounding)
    return z * __builtin_amdgcn_rcpf(1.f + __expf(-z));
}
__device__ __forceinline__ unsigned short f2bf(float x) {
    unsigned int u = __float_as_uint(x);
    u = (u + 0x7FFFu + ((u >> 16) & 1u)) >> 16;
    return (unsigned short)u;
}
__device__ __forceinline__ float bf2f(unsigned short h) {
    return __uint_as_float(((unsigned int)h) << 16);
}
// packed RNE f32x2 -> bf16x2 (v_cvt_pk_bf16_f32 on gfx950)
__device__ __forceinline__ unsigned pk_bf16(float a, float b) {
    union { __hip_bfloat162 h2; unsigned u; } cv;
    cv.h2 = __float22bfloat162_rn(make_float2(a, b));
    return cv.u;
}

// ======================= edge sort by dst (counting sort) ===================
__global__ __launch_bounds__(256) void hist_kernel(
        const int* __restrict__ dst, int* __restrict__ hist)
{
    int e = blockIdx.x * 256 + threadIdx.x;
    if (e < NE) atomicAdd(&hist[dst[e]], 1);
}

__global__ __launch_bounds__(256) void scan1_kernel(
        const int* __restrict__ hist, int* __restrict__ offs, int* __restrict__ bsum)
{
    __shared__ int sh[256];
    const int t = threadIdx.x;
    const int i = blockIdx.x * 256 + t;
    int v = hist[i];
    sh[t] = v;
    __syncthreads();
    for (int off = 1; off < 256; off <<= 1) {
        int x = (t >= off) ? sh[t - off] : 0;
        __syncthreads();
        sh[t] += x;
        __syncthreads();
    }
    offs[i] = sh[t] - v;                 // exclusive
    if (t == 255) bsum[blockIdx.x] = sh[t];
}

__global__ __launch_bounds__(256) void scan2_kernel(int* __restrict__ bsum)
{
    __shared__ int sh[256];
    const int t = threadIdx.x;
    int v = (t < 196) ? bsum[t] : 0;
    sh[t] = v;
    __syncthreads();
    for (int off = 1; off < 256; off <<= 1) {
        int x = (t >= off) ? sh[t - off] : 0;
        __syncthreads();
        sh[t] += x;
        __syncthreads();
    }
    if (t < 196) bsum[t] = sh[t] - v;    // exclusive
}

__global__ __launch_bounds__(256) void scan3_kernel(
        const int* __restrict__ offs, const int* __restrict__ bsum,
        int* __restrict__ cursor)
{
    const int i = blockIdx.x * 256 + threadIdx.x;
    cursor[i] = offs[i] + bsum[blockIdx.x];
}

__global__ __launch_bounds__(256) void scatter_kernel(
        const int* __restrict__ eidx, const float* __restrict__ edist,
        int* __restrict__ cursor,
        int* __restrict__ ssrc, int* __restrict__ sdst, float* __restrict__ sdist)
{
    int e = blockIdx.x * 256 + threadIdx.x;
    if (e < NE) {
        int d = eidx[NE + e];
        int p = atomicAdd(&cursor[d], 1);
        ssrc[p] = eidx[e];
        sdst[p] = d;
        sdist[p] = edist[e];
    }
}

// ======================= weight prep ========================================
__global__ __launch_bounds__(64) void wbig_prep(
        const float* __restrict__ We2, const float* __restrict__ Wn1,
        const float* __restrict__ Wc1, unsigned short* __restrict__ wbig)
{
    const int l = blockIdx.y;
    const int ntile = blockIdx.x / 10;
    const int ks = blockIdx.x % 10;
    const int lane = threadIdx.x;
    const int n = ntile * 16 + (lane & 15);
    const int kbase = ks * 32 + (lane >> 4) * 8;
    const float* Wn1l = Wn1 + (size_t)l * 320 * 256;
    const float* Wc1l = Wc1 + (size_t)l * 320 * 256;
    const float* We2l = We2 + (size_t)l * 64 * 64;
    const float* W1 = (n < 256) ? Wn1l : Wc1l;
    const int nn = n & 255;
    unsigned short* outp = wbig + ((((size_t)l * 32 + ntile) * 10 + ks) * 64 + lane) * 8;
    #pragma unroll
    for (int j = 0; j < 8; ++j) {
        int k = kbase + j;
        float val;
        if (k < 256) {
            val = W1[(size_t)k * 256 + nn];
        } else {
            int i = k - 256;
            float acc = 0.f;
            #pragma unroll 8
            for (int jj = 0; jj < 64; ++jj)
                acc += We2l[i * 64 + jj] * W1[(size_t)(256 + jj) * 256 + nn];
            val = acc;
        }
        outp[j] = f2bf(val);
    }
}

__global__ __launch_bounds__(64) void wn2_prep(
        const float* __restrict__ Wn2, unsigned short* __restrict__ wn2s)
{
    const int l = blockIdx.y;
    const int ntile = blockIdx.x / 8;
    const int ks = blockIdx.x % 8;
    const int lane = threadIdx.x;
    const int n = ntile * 16 + (lane & 15);
    const int kbase = ks * 32 + (lane >> 4) * 8;
    const float* Wn2l = Wn2 + (size_t)l * 256 * 128;
    unsigned short* outp = wn2s + ((((size_t)l * 8 + ntile) * 8 + ks) * 64 + lane) * 8;
    #pragma unroll
    for (int j = 0; j < 8; ++j)
        outp[j] = f2bf(Wn2l[(size_t)(kbase + j) * 128 + n]);
}

// Wc2 as a zero-padded MFMA B fragment set: only n==0 column nonzero.
// [layer][ks(8)][lane(64)][8]
__global__ __launch_bounds__(64) void wc2_prep(
        const float* __restrict__ Wc2, unsigned short* __restrict__ wc2f)
{
    const int l = blockIdx.y;
    const int ks = blockIdx.x;
    const int lane = threadIdx.x;
    const int n = lane & 15;
    const int kbase = ks * 32 + (lane >> 4) * 8;
    const float* Wc2l = Wc2 + l * 256;
    unsigned short* outp = wc2f + (((size_t)l * 8 + ks) * 64 + lane) * 8;
    #pragma unroll
    for (int j = 0; j < 8; ++j)
        outp[j] = (n == 0) ? f2bf(Wc2l[kbase + j]) : (unsigned short)0;
}

__global__ __launch_bounds__(512) void cep_prep(
        const float* __restrict__ be2,
        const float* __restrict__ Wn1, const float* __restrict__ Wc1,
        const float* __restrict__ bn1, const float* __restrict__ bc1,
        float* __restrict__ cep)
{
    const int l = blockIdx.x;
    const int j = threadIdx.x;
    const int jj = j & 255;
    const float* W1 = ((j < 256) ? Wn1 : Wc1) + (size_t)l * 320 * 256;
    const float* be2l = be2 + l * 64;
    float acc = (j < 256) ? bn1[l * 256 + jj] : bc1[l * 256 + jj];
    #pragma unroll 8
    for (int k = 0; k < 64; ++k)
        acc += be2l[k] * W1[(size_t)(256 + k) * 256 + jj];
    cep[l * 512 + j] = acc;
}

__global__ __launch_bounds__(256) void conv_kernel(
        const float* __restrict__ h, unsigned short* __restrict__ hbf)
{
    const int i = (blockIdx.x * 256 + threadIdx.x) * 4;
    float4 v = *(const float4*)(h + i);
    *(uint2*)(hbf + i) = make_uint2(pk_bf16(v.x, v.y), pk_bf16(v.z, v.w));
}

// ======================= fused edge kernel (sorted edges) ===================
__global__ __launch_bounds__(1024) void edge_kernel(
        const int* __restrict__ ssrc, const int* __restrict__ sdst,
        const float* __restrict__ sdist,
        const float* __restrict__ We1l, const float* __restrict__ be1l,
        const unsigned short* __restrict__ hbf,
        const unsigned short* __restrict__ wbig_l,
        const unsigned short* __restrict__ wn2_l,
        const unsigned short* __restrict__ wc2f_l,
        const float* __restrict__ cep_l, const float* __restrict__ bn2l,
        const float* __restrict__ x_in,
        float* __restrict__ h_glob, float* __restrict__ x_out)
{
    __shared__ __align__(16) unsigned short s_A[EPB][328];  // 320 + 8 pad
    __shared__ __align__(16) unsigned short s_t[EPB][520];  // 512 + 8 pad
    __shared__ int s_src[EPB], s_dst[EPB];
    __shared__ unsigned char s_flag[EPB];

    const int tid = threadIdx.x;
    const int eb = blockIdx.x * EPB;

    if (tid < EPB) {
        int sv = ssrc[eb + tid], dv = sdst[eb + tid];
        s_src[tid] = sv;
        s_dst[tid] = dv;
        s_flag[tid] = (tid == EPB - 1) ? 1 : (unsigned char)(dv != sdst[eb + tid + 1]);
    }
    {   // s = silu(d*We1+be1) -> s_A[e][256..319]
        const int e = tid >> 4;
        const int j0 = (tid & 15) * 4;
        const float d = sdist[eb + e];
        float v0 = silu_f(d * We1l[j0 + 0] + be1l[j0 + 0]);
        float v1 = silu_f(d * We1l[j0 + 1] + be1l[j0 + 1]);
        float v2 = silu_f(d * We1l[j0 + 2] + be1l[j0 + 2]);
        float v3 = silu_f(d * We1l[j0 + 3] + be1l[j0 + 3]);
        *(uint2*)&s_A[e][256 + j0] = make_uint2(pk_bf16(v0, v1), pk_bf16(v2, v3));
    }
    __syncthreads();   // s_src/s_dst ready for staging

    // ---- stage h rows: 2048 chunks of 16B ----
    #pragma unroll
    for (int c = tid; c < 2048; c += 1024) {
        const int row = c >> 5, ch = c & 31;
        const int node = (ch < 16) ? s_src[row] : s_dst[row];
        const int koff = (ch & 15) * 8;
        bf16x8 v = *(const bf16x8*)(hbf + (size_t)node * CD + koff);
        *(bf16x8*)&s_A[row][ch * 8] = v;
    }
    __syncthreads();

    const int wave = tid >> 6, lane = tid & 63;
    const int m = lane & 15, q = lane >> 4;

    // ---- GEMM1 ----
    f32x4 acc[2][4];   // [nt][mt]
    #pragma unroll
    for (int nt = 0; nt < 2; ++nt)
        #pragma unroll
        for (int mt = 0; mt < 4; ++mt)
            acc[nt][mt] = (f32x4){0.f, 0.f, 0.f, 0.f};

    #pragma unroll
    for (int ks = 0; ks < 10; ++ks) {
        const int koff = ks * 32 + q * 8;
        bf16x8 a[4];
        #pragma unroll
        for (int mt = 0; mt < 4; ++mt)
            a[mt] = *(const bf16x8*)&s_A[mt * 16 + m][koff];
        #pragma unroll
        for (int nt = 0; nt < 2; ++nt) {
            bf16x8 b = *(const bf16x8*)(wbig_l +
                ((size_t)((wave * 2 + nt) * 10 + ks) * 64 + lane) * 8);
            #pragma unroll
            for (int mt = 0; mt < 4; ++mt)
                acc[nt][mt] = __builtin_amdgcn_mfma_f32_16x16x32_bf16(a[mt], b, acc[nt][mt], 0, 0, 0);
        }
    }
    // epilogue: + cep, silu, packed bf16 -> s_t
    #pragma unroll
    for (int nt = 0; nt < 2; ++nt) {
        const int col = (wave * 2 + nt) * 16 + m;
        const float c = cep_l[col];
        #pragma unroll
        for (int mt = 0; mt < 4; ++mt) {
            float t0 = silu_f(acc[nt][mt][0] + c);
            float t1 = silu_f(acc[nt][mt][1] + c);
            float t2 = silu_f(acc[nt][mt][2] + c);
            float t3 = silu_f(acc[nt][mt][3] + c);
            unsigned u0 = pk_bf16(t0, t1);
            unsigned u1 = pk_bf16(t2, t3);
            const int r = mt * 16 + q * 4;
            s_t[r + 0][col] = (unsigned short)u0;
            s_t[r + 1][col] = (unsigned short)(u0 >> 16);
            s_t[r + 2][col] = (unsigned short)u1;
            s_t[r + 3][col] = (unsigned short)(u1 >> 16);
        }
    }
    __syncthreads();

    // ---- GEMM2 (+ coord MFMA on waves 0..3) ----
    f32x4 acc2[2];
    acc2[0] = (f32x4){0.f, 0.f, 0.f, 0.f};
    acc2[1] = (f32x4){0.f, 0.f, 0.f, 0.f};
    const int ct = wave >> 1;            // col tile 0..7
    const int mbase = (wave & 1) * 2;    // mtiles {mbase, mbase+1}
    #pragma unroll
    for (int ks = 0; ks < 8; ++ks) {
        bf16x8 a0 = *(const bf16x8*)&s_t[mbase * 16 + m][ks * 32 + q * 8];
        bf16x8 a1 = *(const bf16x8*)&s_t[(mbase + 1) * 16 + m][ks * 32 + q * 8];
        bf16x8 b = *(const bf16x8*)(wn2_l + ((size_t)(ct * 8 + ks) * 64 + lane) * 8);
        acc2[0] = __builtin_amdgcn_mfma_f32_16x16x32_bf16(a0, b, acc2[0], 0, 0, 0);
        acc2[1] = __builtin_amdgcn_mfma_f32_16x16x32_bf16(a1, b, acc2[1], 0, 0, 0);
    }

    if (wave < 4) {
        // coord dot as MFMA: A = t[wave*16.., 256:512], B = zero-padded Wc2
        f32x4 acc3 = (f32x4){0.f, 0.f, 0.f, 0.f};
        #pragma unroll
        for (int ks = 0; ks < 8; ++ks) {
            bf16x8 a = *(const bf16x8*)&s_t[wave * 16 + m][256 + ks * 32 + q * 8];
            bf16x8 b = *(const bf16x8*)(wc2f_l + ((size_t)ks * 64 + lane) * 8);
            acc3 = __builtin_amdgcn_mfma_f32_16x16x32_bf16(a, b, acc3, 0, 0, 0);
        }
        if (m == 0) {   // col 0 holds the dot; rows q*4+i
            #pragma unroll
            for (int i = 0; i < 4; ++i) {
                const int e = wave * 16 + q * 4 + i;
                const float cw = acc3[i];
                const int sn = s_src[e], dn = s_dst[e];
                float dx0 = x_in[sn * 3 + 0] - x_in[dn * 3 + 0];
                float dx1 = x_in[sn * 3 + 1] - x_in[dn * 3 + 1];
                float dx2 = x_in[sn * 3 + 2] - x_in[dn * 3 + 2];
                atomicAdd(&x_out[dn * 3 + 0], cw * dx0);
                atomicAdd(&x_out[dn * 3 + 1], cw * dx1);
                atomicAdd(&x_out[dn * 3 + 2], cw * dx2);
            }
        }
    }
    __syncthreads();   // all GEMM2/coord reads of s_t done

    // write m into t_h (fp32, aliases s_t bytes [0,512) of each row)
    {
        const int col = ct * 16 + m;
        const float bb = bn2l[col];
        #pragma unroll
        for (int u = 0; u < 2; ++u) {
            #pragma unroll
            for (int i = 0; i < 4; ++i) {
                const int e = (mbase + u) * 16 + q * 4 + i;
                float* th = (float*)((char*)&s_t[0][0] + (size_t)e * 1040);
                th[col] = acc2[u][i] + bb;
            }
        }
    }
    __syncthreads();

    // ---- segmented h reduction: waves 14-15, runs of equal dst ----
    if (tid >= 896) {
        const int col = tid & 127;
        float val = 0.f;
        #pragma unroll 4
        for (int e = 0; e < EPB; ++e) {
            const float* th = (const float*)((const char*)&s_t[0][0] + (size_t)e * 1040);
            val += th[col];
            if (s_flag[e]) {
                atomicAdd(&h_glob[(size_t)s_dst[e] * CD + col], val);
                val = 0.f;
            }
        }
    }
}

// ======================= final layernorm ====================================
__global__ __launch_bounds__(256) void final_kernel(
        const float* __restrict__ h, const float* __restrict__ x,
        const float* __restrict__ gamma, const float* __restrict__ beta,
        float* __restrict__ out)
{
    const int lane = threadIdx.x & 63;
    const int wave = threadIdx.x >> 6;
    const int n = blockIdx.x * 4 + wave;
    float v0 = h[(size_t)n * CD + lane];
    float v1 = h[(size_t)n * CD + 64 + lane];
    float ssum = v0 + v1;
    for (int off = 32; off; off >>= 1) ssum += __shfl_xor(ssum, off);
    float mu = ssum * (1.f / 128.f);
    float d0 = v0 - mu, d1 = v1 - mu;
    float sq = d0 * d0 + d1 * d1;
    for (int off = 32; off; off >>= 1) sq += __shfl_xor(sq, off);
    float rstd = rsqrtf(sq * (1.f / 128.f) + 1e-5f);
    out[(size_t)n * CD + lane]      = gamma[lane]      * d0 * rstd + beta[lane];
    out[(size_t)n * CD + 64 + lane] = gamma[64 + lane] * d1 * rstd + beta[64 + lane];
    if (threadIdx.x < 12) {
        int nn = blockIdx.x * 4 + threadIdx.x / 3;
        int c = threadIdx.x % 3;
        out[(size_t)NN * CD + nn * 3 + c] = x[nn * 3 + c];
    }
}

static inline size_t align_up(size_t v) { return (v + 255) & ~(size_t)255; }

extern "C" void kernel_launch(void* const* d_in, const int* in_sizes, int n_in,
                              void* d_out, int out_size, void* d_ws, size_t ws_size,
                              hipStream_t stream)
{
    const float* single = (const float*)d_in[0];
    const float* coords = (const float*)d_in[2];
    const int*   eidx   = (const int*)d_in[3];
    const float* edist  = (const float*)d_in[4];
    const float* We1 = (const float*)d_in[5];
    const float* be1 = (const float*)d_in[6];
    const float* We2 = (const float*)d_in[7];
    const float* be2 = (const float*)d_in[8];
    const float* Wn1 = (const float*)d_in[9];
    const float* bn1 = (const float*)d_in[10];
    const float* Wn2 = (const float*)d_in[11];
    const float* bn2 = (const float*)d_in[12];
    const float* Wc1 = (const float*)d_in[13];
    const float* bc1 = (const float*)d_in[14];
    const float* Wc2 = (const float*)d_in[15];
    const float* gamma = (const float*)d_in[16];
    const float* beta  = (const float*)d_in[17];
    float* out = (float*)d_out;

    char* w = (char*)d_ws;
    float* h0  = (float*)w;  w += align_up((size_t)NN * CD * 4);
    float* x0  = (float*)w;  w += align_up((size_t)NN * 3 * 4);
    float* x1  = (float*)w;  w += align_up((size_t)NN * 3 * 4);
    unsigned short* hbf  = (unsigned short*)w; w += align_up((size_t)NN * CD * 2);
    unsigned short* wbig = (unsigned short*)w; w += align_up((size_t)4 * 512 * 320 * 2);
    unsigned short* wn2s = (unsigned short*)w; w += align_up((size_t)4 * 256 * 128 * 2);
    unsigned short* wc2f = (unsigned short*)w; w += align_up((size_t)4 * 8 * 64 * 8 * 2);
    float* cep = (float*)w;  w += align_up((size_t)4 * 512 * 4);
    int* hist   = (int*)w;   w += align_up((size_t)HBINS * 4);
    int* offs   = (int*)w;   w += align_up((size_t)HBINS * 4);
    int* cursor = (int*)w;   w += align_up((size_t)HBINS * 4);
    int* bsum   = (int*)w;   w += align_up((size_t)256 * 4);
    int* ssrc   = (int*)w;   w += align_up((size_t)NE * 4);
    int* sdst   = (int*)w;   w += align_up((size_t)NE * 4);
    float* sdist = (float*)w; w += align_up((size_t)NE * 4);

    // ---- sort edges by dst (once; constant across layers) ----
    hipMemsetAsync(hist, 0, (size_t)HBINS * 4, stream);
    hist_kernel<<<(NE + 255) / 256, 256, 0, stream>>>(eidx + NE, hist);
    scan1_kernel<<<HBINS / 256, 256, 0, stream>>>(hist, offs, bsum);
    scan2_kernel<<<1, 256, 0, stream>>>(bsum);
    scan3_kernel<<<HBINS / 256, 256, 0, stream>>>(offs, bsum, cursor);
    scatter_kernel<<<(NE + 255) / 256, 256, 0, stream>>>(eidx, edist, cursor, ssrc, sdst, sdist);

    // ---- weight prep ----
    wbig_prep<<<dim3(320, 4), 64, 0, stream>>>(We2, Wn1, Wc1, wbig);
    wn2_prep<<<dim3(64, 4), 64, 0, stream>>>(Wn2, wn2s);
    wc2_prep<<<dim3(8, 4), 64, 0, stream>>>(Wc2, wc2f);
    cep_prep<<<4, 512, 0, stream>>>(be2, Wn1, Wc1, bn1, bc1, cep);

    hipMemcpyAsync(h0, single, (size_t)NN * CD * 4, hipMemcpyDeviceToDevice, stream);
    hipMemcpyAsync(x0, coords, (size_t)NN * 3 * 4, hipMemcpyDeviceToDevice, stream);

    float* xc = x0; float* xn = x1;
    for (int l = 0; l < 4; ++l) {
        conv_kernel<<<(NN * CD) / 1024, 256, 0, stream>>>(h0, hbf);
        hipMemcpyAsync(xn, xc, (size_t)NN * 3 * 4, hipMemcpyDeviceToDevice, stream);
        edge_kernel<<<NE / EPB, 1024, 0, stream>>>(
            ssrc, sdst, sdist,
            We1 + l * 64, be1 + l * 64,
            hbf,
            wbig + (size_t)l * 512 * 320,
            wn2s + (size_t)l * 256 * 128,
            wc2f + (size_t)l * 8 * 64 * 8,
            cep + l * 512, bn2 + l * CD,
            xc, h0, xn);
        float* t = xc; xc = xn; xn = t;
    }
    final_kernel<<<NN / 4, 256, 0, stream>>>(h0, xc, gamma, beta, out);
}

// Round 6
// 1519.795 us; speedup vs baseline: 1.7152x; 1.1100x over previous
//
#include <hip/hip_runtime.h>
#include <hip/hip_bf16.h>
#include <math.h>

#define NN 50000
#define NE 400000
#define CD 128
#define EPB 32          // edges per block in edge_kernel
#define HBINS 50176     // 196*256, >= NN

typedef __attribute__((ext_vector_type(8))) short bf16x8;
typedef __attribute__((ext_vector_type(4))) float f32x4;

__device__ __forceinline__ float silu_f(float z) {
    // z / (1+e^-z) with hardware v_rcp_f32 (~1 ulp; invisible vs bf16 rounding)
    return z * __builtin_amdgcn_rcpf(1.f + __expf(-z));
}
__device__ __forceinline__ unsigned short f2bf(float x) {
    unsigned int u = __float_as_uint(x);
    u = (u + 0x7FFFu + ((u >> 16) & 1u)) >> 16;
    return (unsigned short)u;
}
__device__ __forceinline__ float bf2f(unsigned short h) {
    return __uint_as_float(((unsigned int)h) << 16);
}
// packed RNE f32x2 -> bf16x2 (v_cvt_pk_bf16_f32 on gfx950)
__device__ __forceinline__ unsigned pk_bf16(float a, float b) {
    union { __hip_bfloat162 h2; unsigned u; } cv;
    cv.h2 = __float22bfloat162_rn(make_float2(a, b));
    return cv.u;
}

// ======================= edge sort by dst (counting sort) ===================
__global__ __launch_bounds__(256) void hist_kernel(
        const int* __restrict__ dst, int* __restrict__ hist)
{
    int e = blockIdx.x * 256 + threadIdx.x;
    if (e < NE) atomicAdd(&hist[dst[e]], 1);
}

__global__ __launch_bounds__(256) void scan1_kernel(
        const int* __restrict__ hist, int* __restrict__ offs, int* __restrict__ bsum)
{
    __shared__ int sh[256];
    const int t = threadIdx.x;
    const int i = blockIdx.x * 256 + t;
    int v = hist[i];
    sh[t] = v;
    __syncthreads();
    for (int off = 1; off < 256; off <<= 1) {
        int x = (t >= off) ? sh[t - off] : 0;
        __syncthreads();
        sh[t] += x;
        __syncthreads();
    }
    offs[i] = sh[t] - v;                 // exclusive
    if (t == 255) bsum[blockIdx.x] = sh[t];
}

__global__ __launch_bounds__(256) void scan2_kernel(int* __restrict__ bsum)
{
    __shared__ int sh[256];
    const int t = threadIdx.x;
    int v = (t < 196) ? bsum[t] : 0;
    sh[t] = v;
    __syncthreads();
    for (int off = 1; off < 256; off <<= 1) {
        int x = (t >= off) ? sh[t - off] : 0;
        __syncthreads();
        sh[t] += x;
        __syncthreads();
    }
    if (t < 196) bsum[t] = sh[t] - v;    // exclusive
}

__global__ __launch_bounds__(256) void scan3_kernel(
        const int* __restrict__ offs, const int* __restrict__ bsum,
        int* __restrict__ cursor)
{
    const int i = blockIdx.x * 256 + threadIdx.x;
    cursor[i] = offs[i] + bsum[blockIdx.x];
}

__global__ __launch_bounds__(256) void scatter_kernel(
        const int* __restrict__ eidx, const float* __restrict__ edist,
        int* __restrict__ cursor,
        int* __restrict__ ssrc, int* __restrict__ sdst, float* __restrict__ sdist)
{
    int e = blockIdx.x * 256 + threadIdx.x;
    if (e < NE) {
        int d = eidx[NE + e];
        int p = atomicAdd(&cursor[d], 1);
        ssrc[p] = eidx[e];
        sdst[p] = d;
        sdist[p] = edist[e];
    }
}

// ======================= weight prep ========================================
__global__ __launch_bounds__(64) void wbig_prep(
        const float* __restrict__ We2, const float* __restrict__ Wn1,
        const float* __restrict__ Wc1, unsigned short* __restrict__ wbig)
{
    const int l = blockIdx.y;
    const int ntile = blockIdx.x / 10;
    const int ks = blockIdx.x % 10;
    const int lane = threadIdx.x;
    const int n = ntile * 16 + (lane & 15);
    const int kbase = ks * 32 + (lane >> 4) * 8;
    const float* Wn1l = Wn1 + (size_t)l * 320 * 256;
    const float* Wc1l = Wc1 + (size_t)l * 320 * 256;
    const float* We2l = We2 + (size_t)l * 64 * 64;
    const float* W1 = (n < 256) ? Wn1l : Wc1l;
    const int nn = n & 255;
    unsigned short* outp = wbig + ((((size_t)l * 32 + ntile) * 10 + ks) * 64 + lane) * 8;
    #pragma unroll
    for (int j = 0; j < 8; ++j) {
        int k = kbase + j;
        float val;
        if (k < 256) {
            val = W1[(size_t)k * 256 + nn];
        } else {
            int i = k - 256;
            float acc = 0.f;
            #pragma unroll 8
            for (int jj = 0; jj < 64; ++jj)
                acc += We2l[i * 64 + jj] * W1[(size_t)(256 + jj) * 256 + nn];
            val = acc;
        }
        outp[j] = f2bf(val);
    }
}

__global__ __launch_bounds__(64) void wn2_prep(
        const float* __restrict__ Wn2, unsigned short* __restrict__ wn2s)
{
    const int l = blockIdx.y;
    const int ntile = blockIdx.x / 8;
    const int ks = blockIdx.x % 8;
    const int lane = threadIdx.x;
    const int n = ntile * 16 + (lane & 15);
    const int kbase = ks * 32 + (lane >> 4) * 8;
    const float* Wn2l = Wn2 + (size_t)l * 256 * 128;
    unsigned short* outp = wn2s + ((((size_t)l * 8 + ntile) * 8 + ks) * 64 + lane) * 8;
    #pragma unroll
    for (int j = 0; j < 8; ++j)
        outp[j] = f2bf(Wn2l[(size_t)(kbase + j) * 128 + n]);
}

// Wc2 as a zero-padded MFMA B fragment set: only n==0 column nonzero.
// [layer][ks(8)][lane(64)][8]
__global__ __launch_bounds__(64) void wc2_prep(
        const float* __restrict__ Wc2, unsigned short* __restrict__ wc2f)
{
    const int l = blockIdx.y;
    const int ks = blockIdx.x;
    const int lane = threadIdx.x;
    const int n = lane & 15;
    const int kbase = ks * 32 + (lane >> 4) * 8;
    const float* Wc2l = Wc2 + l * 256;
    unsigned short* outp = wc2f + (((size_t)l * 8 + ks) * 64 + lane) * 8;
    #pragma unroll
    for (int j = 0; j < 8; ++j)
        outp[j] = (n == 0) ? f2bf(Wc2l[kbase + j]) : (unsigned short)0;
}

__global__ __launch_bounds__(512) void cep_prep(
        const float* __restrict__ be2,
        const float* __restrict__ Wn1, const float* __restrict__ Wc1,
        const float* __restrict__ bn1, const float* __restrict__ bc1,
        float* __restrict__ cep)
{
    const int l = blockIdx.x;
    const int j = threadIdx.x;
    const int jj = j & 255;
    const float* W1 = ((j < 256) ? Wn1 : Wc1) + (size_t)l * 320 * 256;
    const float* be2l = be2 + l * 64;
    float acc = (j < 256) ? bn1[l * 256 + jj] : bc1[l * 256 + jj];
    #pragma unroll 8
    for (int k = 0; k < 64; ++k)
        acc += be2l[k] * W1[(size_t)(256 + k) * 256 + jj];
    cep[l * 512 + j] = acc;
}

__global__ __launch_bounds__(256) void conv_kernel(
        const float* __restrict__ h, unsigned short* __restrict__ hbf)
{
    const int i = (blockIdx.x * 256 + threadIdx.x) * 4;
    float4 v = *(const float4*)(h + i);
    *(uint2*)(hbf + i) = make_uint2(pk_bf16(v.x, v.y), pk_bf16(v.z, v.w));
}

// ======================= fused edge kernel (sorted edges) ===================
// 32 edges/block, 512 threads (8 waves), ~55 KB LDS -> 2 blocks/CU resident.
// GEMM1: wave w: ntiles {4w..4w+3}, mtiles {0,1}.
// GEMM2: wave w: coltile w, mtiles {0,1}.
// coord: waves 0-1 (MFMA with zero-padded Wc2 B-frags).
// segsum: waves 6-7 (128 cols).
// ---------------------------------------------------------------------------
__global__ __launch_bounds__(512) void edge_kernel(
        const int* __restrict__ ssrc, const int* __restrict__ sdst,
        const float* __restrict__ sdist,
        const float* __restrict__ We1l, const float* __restrict__ be1l,
        const unsigned short* __restrict__ hbf,
        const unsigned short* __restrict__ wbig_l,
        const unsigned short* __restrict__ wn2_l,
        const unsigned short* __restrict__ wc2f_l,
        const float* __restrict__ cep_l, const float* __restrict__ bn2l,
        const float* __restrict__ x_in,
        float* __restrict__ h_glob, float* __restrict__ x_out)
{
    __shared__ __align__(16) unsigned short s_A[EPB][328];  // 320 + 8 pad
    __shared__ __align__(16) unsigned short s_t[EPB][520];  // 512 + 8 pad
    __shared__ int s_src[EPB], s_dst[EPB];
    __shared__ unsigned char s_flag[EPB];

    const int tid = threadIdx.x;
    const int eb = blockIdx.x * EPB;

    if (tid < EPB) {
        int sv = ssrc[eb + tid], dv = sdst[eb + tid];
        s_src[tid] = sv;
        s_dst[tid] = dv;
        s_flag[tid] = (tid == EPB - 1) ? 1 : (unsigned char)(dv != sdst[eb + tid + 1]);
    }
    {   // s = silu(d*We1+be1) -> s_A[e][256..319]; 16 threads/edge, 4 cols each
        const int e = tid >> 4;
        const int j0 = (tid & 15) * 4;
        const float d = sdist[eb + e];
        float v0 = silu_f(d * We1l[j0 + 0] + be1l[j0 + 0]);
        float v1 = silu_f(d * We1l[j0 + 1] + be1l[j0 + 1]);
        float v2 = silu_f(d * We1l[j0 + 2] + be1l[j0 + 2]);
        float v3 = silu_f(d * We1l[j0 + 3] + be1l[j0 + 3]);
        *(uint2*)&s_A[e][256 + j0] = make_uint2(pk_bf16(v0, v1), pk_bf16(v2, v3));
    }
    __syncthreads();   // s_src/s_dst ready for staging

    // ---- stage h rows: 1024 chunks of 16B ----
    #pragma unroll
    for (int c = tid; c < 1024; c += 512) {
        const int row = c >> 5, ch = c & 31;
        const int node = (ch < 16) ? s_src[row] : s_dst[row];
        const int koff = (ch & 15) * 8;
        bf16x8 v = *(const bf16x8*)(hbf + (size_t)node * CD + koff);
        *(bf16x8*)&s_A[row][ch * 8] = v;
    }
    __syncthreads();

    const int wave = tid >> 6, lane = tid & 63;
    const int m = lane & 15, q = lane >> 4;

    // ---- GEMM1 ----
    f32x4 acc[4][2];   // [nt][mt]
    #pragma unroll
    for (int nt = 0; nt < 4; ++nt)
        #pragma unroll
        for (int mt = 0; mt < 2; ++mt)
            acc[nt][mt] = (f32x4){0.f, 0.f, 0.f, 0.f};

    #pragma unroll
    for (int ks = 0; ks < 10; ++ks) {
        const int koff = ks * 32 + q * 8;
        bf16x8 a0 = *(const bf16x8*)&s_A[m][koff];
        bf16x8 a1 = *(const bf16x8*)&s_A[16 + m][koff];
        #pragma unroll
        for (int nt = 0; nt < 4; ++nt) {
            bf16x8 b = *(const bf16x8*)(wbig_l +
                ((size_t)((wave * 4 + nt) * 10 + ks) * 64 + lane) * 8);
            acc[nt][0] = __builtin_amdgcn_mfma_f32_16x16x32_bf16(a0, b, acc[nt][0], 0, 0, 0);
            acc[nt][1] = __builtin_amdgcn_mfma_f32_16x16x32_bf16(a1, b, acc[nt][1], 0, 0, 0);
        }
    }
    // epilogue: + cep, silu, packed bf16 -> s_t
    #pragma unroll
    for (int nt = 0; nt < 4; ++nt) {
        const int col = (wave * 4 + nt) * 16 + m;
        const float c = cep_l[col];
        #pragma unroll
        for (int mt = 0; mt < 2; ++mt) {
            float t0 = silu_f(acc[nt][mt][0] + c);
            float t1 = silu_f(acc[nt][mt][1] + c);
            float t2 = silu_f(acc[nt][mt][2] + c);
            float t3 = silu_f(acc[nt][mt][3] + c);
            unsigned u0 = pk_bf16(t0, t1);
            unsigned u1 = pk_bf16(t2, t3);
            const int r = mt * 16 + q * 4;
            s_t[r + 0][col] = (unsigned short)u0;
            s_t[r + 1][col] = (unsigned short)(u0 >> 16);
            s_t[r + 2][col] = (unsigned short)u1;
            s_t[r + 3][col] = (unsigned short)(u1 >> 16);
        }
    }
    __syncthreads();

    // ---- GEMM2 (+ coord MFMA on waves 0..1) ----
    f32x4 acc2[2];
    acc2[0] = (f32x4){0.f, 0.f, 0.f, 0.f};
    acc2[1] = (f32x4){0.f, 0.f, 0.f, 0.f};
    const int ct = wave;                 // col tile 0..7
    #pragma unroll
    for (int ks = 0; ks < 8; ++ks) {
        bf16x8 a0 = *(const bf16x8*)&s_t[m][ks * 32 + q * 8];
        bf16x8 a1 = *(const bf16x8*)&s_t[16 + m][ks * 32 + q * 8];
        bf16x8 b = *(const bf16x8*)(wn2_l + ((size_t)(ct * 8 + ks) * 64 + lane) * 8);
        acc2[0] = __builtin_amdgcn_mfma_f32_16x16x32_bf16(a0, b, acc2[0], 0, 0, 0);
        acc2[1] = __builtin_amdgcn_mfma_f32_16x16x32_bf16(a1, b, acc2[1], 0, 0, 0);
    }

    if (wave < 2) {
        // coord dot as MFMA: A = t[wave*16.., 256:512], B = zero-padded Wc2
        f32x4 acc3 = (f32x4){0.f, 0.f, 0.f, 0.f};
        #pragma unroll
        for (int ks = 0; ks < 8; ++ks) {
            bf16x8 a = *(const bf16x8*)&s_t[wave * 16 + m][256 + ks * 32 + q * 8];
            bf16x8 b = *(const bf16x8*)(wc2f_l + ((size_t)ks * 64 + lane) * 8);
            acc3 = __builtin_amdgcn_mfma_f32_16x16x32_bf16(a, b, acc3, 0, 0, 0);
        }
        if (m == 0) {   // col 0 holds the dot; rows q*4+i
            #pragma unroll
            for (int i = 0; i < 4; ++i) {
                const int e = wave * 16 + q * 4 + i;
                const float cw = acc3[i];
                const int sn = s_src[e], dn = s_dst[e];
                float dx0 = x_in[sn * 3 + 0] - x_in[dn * 3 + 0];
                float dx1 = x_in[sn * 3 + 1] - x_in[dn * 3 + 1];
                float dx2 = x_in[sn * 3 + 2] - x_in[dn * 3 + 2];
                atomicAdd(&x_out[dn * 3 + 0], cw * dx0);
                atomicAdd(&x_out[dn * 3 + 1], cw * dx1);
                atomicAdd(&x_out[dn * 3 + 2], cw * dx2);
            }
        }
    }
    __syncthreads();   // all GEMM2/coord reads of s_t done

    // write m into t_h (fp32, aliases s_t bytes [0,512) of each row)
    {
        const int col = ct * 16 + m;
        const float bb = bn2l[col];
        #pragma unroll
        for (int u = 0; u < 2; ++u) {
            #pragma unroll
            for (int i = 0; i < 4; ++i) {
                const int e = u * 16 + q * 4 + i;
                float* th = (float*)((char*)&s_t[0][0] + (size_t)e * 1040);
                th[col] = acc2[u][i] + bb;
            }
        }
    }
    __syncthreads();

    // ---- segmented h reduction: waves 6-7, runs of equal dst ----
    if (tid >= 384) {
        const int col = tid & 127;
        float val = 0.f;
        #pragma unroll 4
        for (int e = 0; e < EPB; ++e) {
            const float* th = (const float*)((const char*)&s_t[0][0] + (size_t)e * 1040);
            val += th[col];
            if (s_flag[e]) {
                atomicAdd(&h_glob[(size_t)s_dst[e] * CD + col], val);
                val = 0.f;
            }
        }
    }
}

// ======================= final layernorm ====================================
__global__ __launch_bounds__(256) void final_kernel(
        const float* __restrict__ h, const float* __restrict__ x,
        const float* __restrict__ gamma, const float* __restrict__ beta,
        float* __restrict__ out)
{
    const int lane = threadIdx.x & 63;
    const int wave = threadIdx.x >> 6;
    const int n = blockIdx.x * 4 + wave;
    float v0 = h[(size_t)n * CD + lane];
    float v1 = h[(size_t)n * CD + 64 + lane];
    float ssum = v0 + v1;
    for (int off = 32; off; off >>= 1) ssum += __shfl_xor(ssum, off);
    float mu = ssum * (1.f / 128.f);
    float d0 = v0 - mu, d1 = v1 - mu;
    float sq = d0 * d0 + d1 * d1;
    for (int off = 32; off; off >>= 1) sq += __shfl_xor(sq, off);
    float rstd = rsqrtf(sq * (1.f / 128.f) + 1e-5f);
    out[(size_t)n * CD + lane]      = gamma[lane]      * d0 * rstd + beta[lane];
    out[(size_t)n * CD + 64 + lane] = gamma[64 + lane] * d1 * rstd + beta[64 + lane];
    if (threadIdx.x < 12) {
        int nn = blockIdx.x * 4 + threadIdx.x / 3;
        int c = threadIdx.x % 3;
        out[(size_t)NN * CD + nn * 3 + c] = x[nn * 3 + c];
    }
}

static inline size_t align_up(size_t v) { return (v + 255) & ~(size_t)255; }

extern "C" void kernel_launch(void* const* d_in, const int* in_sizes, int n_in,
                              void* d_out, int out_size, void* d_ws, size_t ws_size,
                              hipStream_t stream)
{
    const float* single = (const float*)d_in[0];
    const float* coords = (const float*)d_in[2];
    const int*   eidx   = (const int*)d_in[3];
    const float* edist  = (const float*)d_in[4];
    const float* We1 = (const float*)d_in[5];
    const float* be1 = (const float*)d_in[6];
    const float* We2 = (const float*)d_in[7];
    const float* be2 = (const float*)d_in[8];
    const float* Wn1 = (const float*)d_in[9];
    const float* bn1 = (const float*)d_in[10];
    const float* Wn2 = (const float*)d_in[11];
    const float* bn2 = (const float*)d_in[12];
    const float* Wc1 = (const float*)d_in[13];
    const float* bc1 = (const float*)d_in[14];
    const float* Wc2 = (const float*)d_in[15];
    const float* gamma = (const float*)d_in[16];
    const float* beta  = (const float*)d_in[17];
    float* out = (float*)d_out;

    char* w = (char*)d_ws;
    float* h0  = (float*)w;  w += align_up((size_t)NN * CD * 4);
    float* x0  = (float*)w;  w += align_up((size_t)NN * 3 * 4);
    float* x1  = (float*)w;  w += align_up((size_t)NN * 3 * 4);
    unsigned short* hbf  = (unsigned short*)w; w += align_up((size_t)NN * CD * 2);
    unsigned short* wbig = (unsigned short*)w; w += align_up((size_t)4 * 512 * 320 * 2);
    unsigned short* wn2s = (unsigned short*)w; w += align_up((size_t)4 * 256 * 128 * 2);
    unsigned short* wc2f = (unsigned short*)w; w += align_up((size_t)4 * 8 * 64 * 8 * 2);
    float* cep = (float*)w;  w += align_up((size_t)4 * 512 * 4);
    int* hist   = (int*)w;   w += align_up((size_t)HBINS * 4);
    int* offs   = (int*)w;   w += align_up((size_t)HBINS * 4);
    int* cursor = (int*)w;   w += align_up((size_t)HBINS * 4);
    int* bsum   = (int*)w;   w += align_up((size_t)256 * 4);
    int* ssrc   = (int*)w;   w += align_up((size_t)NE * 4);
    int* sdst   = (int*)w;   w += align_up((size_t)NE * 4);
    float* sdist = (float*)w; w += align_up((size_t)NE * 4);

    // ---- sort edges by dst (once; constant across layers) ----
    hipMemsetAsync(hist, 0, (size_t)HBINS * 4, stream);
    hist_kernel<<<(NE + 255) / 256, 256, 0, stream>>>(eidx + NE, hist);
    scan1_kernel<<<HBINS / 256, 256, 0, stream>>>(hist, offs, bsum);
    scan2_kernel<<<1, 256, 0, stream>>>(bsum);
    scan3_kernel<<<HBINS / 256, 256, 0, stream>>>(offs, bsum, cursor);
    scatter_kernel<<<(NE + 255) / 256, 256, 0, stream>>>(eidx, edist, cursor, ssrc, sdst, sdist);

    // ---- weight prep ----
    wbig_prep<<<dim3(320, 4), 64, 0, stream>>>(We2, Wn1, Wc1, wbig);
    wn2_prep<<<dim3(64, 4), 64, 0, stream>>>(Wn2, wn2s);
    wc2_prep<<<dim3(8, 4), 64, 0, stream>>>(Wc2, wc2f);
    cep_prep<<<4, 512, 0, stream>>>(be2, Wn1, Wc1, bn1, bc1, cep);

    hipMemcpyAsync(h0, single, (size_t)NN * CD * 4, hipMemcpyDeviceToDevice, stream);
    hipMemcpyAsync(x0, coords, (size_t)NN * 3 * 4, hipMemcpyDeviceToDevice, stream);

    float* xc = x0; float* xn = x1;
    for (int l = 0; l < 4; ++l) {
        conv_kernel<<<(NN * CD) / 1024, 256, 0, stream>>>(h0, hbf);
        hipMemcpyAsync(xn, xc, (size_t)NN * 3 * 4, hipMemcpyDeviceToDevice, stream);
        edge_kernel<<<NE / EPB, 512, 0, stream>>>(
            ssrc, sdst, sdist,
            We1 + l * 64, be1 + l * 64,
            hbf,
            wbig + (size_t)l * 512 * 320,
            wn2s + (size_t)l * 256 * 128,
            wc2f + (size_t)l * 8 * 64 * 8,
            cep + l * 512, bn2 + l * CD,
            xc, h0, xn);
        float* t = xc; xc = xn; xn = t;
    }
    final_kernel<<<NN / 4, 256, 0, stream>>>(h0, xc, gamma, beta, out);
}

// Round 7
// 1426.054 us; speedup vs baseline: 1.8279x; 1.0657x over previous
//
#include <hip/hip_runtime.h>
#include <hip/hip_bf16.h>
#include <math.h>

#define NN 50000
#define NE 400000
#define CD 128
#define EPB 64          // edges per block in edge_kernel
#define HBINS 50176     // 196*256, >= NN

typedef __attribute__((ext_vector_type(8))) short bf16x8;
typedef __attribute__((ext_vector_type(4))) float f32x4;

__device__ __forceinline__ float silu_f(float z) {
    return z * __builtin_amdgcn_rcpf(1.f + __expf(-z));
}
__device__ __forceinline__ unsigned short f2bf(float x) {
    unsigned int u = __float_as_uint(x);
    u = (u + 0x7FFFu + ((u >> 16) & 1u)) >> 16;
    return (unsigned short)u;
}
__device__ __forceinline__ float bf2f(unsigned short h) {
    return __uint_as_float(((unsigned int)h) << 16);
}
__device__ __forceinline__ unsigned pk_bf16(float a, float b) {
    union { __hip_bfloat162 h2; unsigned u; } cv;
    cv.h2 = __float22bfloat162_rn(make_float2(a, b));
    return cv.u;
}

// ======================= edge sort by dst (counting sort) ===================
__global__ __launch_bounds__(256) void hist_kernel(
        const int* __restrict__ dst, int* __restrict__ hist)
{
    int e = blockIdx.x * 256 + threadIdx.x;
    if (e < NE) atomicAdd(&hist[dst[e]], 1);
}

__global__ __launch_bounds__(256) void scan1_kernel(
        const int* __restrict__ hist, int* __restrict__ offs, int* __restrict__ bsum)
{
    __shared__ int sh[256];
    const int t = threadIdx.x;
    const int i = blockIdx.x * 256 + t;
    int v = hist[i];
    sh[t] = v;
    __syncthreads();
    for (int off = 1; off < 256; off <<= 1) {
        int x = (t >= off) ? sh[t - off] : 0;
        __syncthreads();
        sh[t] += x;
        __syncthreads();
    }
    offs[i] = sh[t] - v;                 // exclusive
    if (t == 255) bsum[blockIdx.x] = sh[t];
}

__global__ __launch_bounds__(256) void scan2_kernel(int* __restrict__ bsum)
{
    __shared__ int sh[256];
    const int t = threadIdx.x;
    int v = (t < 196) ? bsum[t] : 0;
    sh[t] = v;
    __syncthreads();
    for (int off = 1; off < 256; off <<= 1) {
        int x = (t >= off) ? sh[t - off] : 0;
        __syncthreads();
        sh[t] += x;
        __syncthreads();
    }
    if (t < 196) bsum[t] = sh[t] - v;    // exclusive
}

__global__ __launch_bounds__(256) void scan3_kernel(
        const int* __restrict__ offs, const int* __restrict__ bsum,
        int* __restrict__ cursor)
{
    const int i = blockIdx.x * 256 + threadIdx.x;
    cursor[i] = offs[i] + bsum[blockIdx.x];
}

__global__ __launch_bounds__(256) void scatter_kernel(
        const int* __restrict__ eidx, const float* __restrict__ edist,
        int* __restrict__ cursor,
        int* __restrict__ ssrc, int* __restrict__ sdst, float* __restrict__ sdist)
{
    int e = blockIdx.x * 256 + threadIdx.x;
    if (e < NE) {
        int d = eidx[NE + e];
        int p = atomicAdd(&cursor[d], 1);
        ssrc[p] = eidx[e];
        sdst[p] = d;
        sdist[p] = edist[e];
    }
}

// ======================= weight prep ========================================
__global__ __launch_bounds__(64) void wbig_prep(
        const float* __restrict__ We2, const float* __restrict__ Wn1,
        const float* __restrict__ Wc1, unsigned short* __restrict__ wbig)
{
    const int l = blockIdx.y;
    const int ntile = blockIdx.x / 10;
    const int ks = blockIdx.x % 10;
    const int lane = threadIdx.x;
    const int n = ntile * 16 + (lane & 15);
    const int kbase = ks * 32 + (lane >> 4) * 8;
    const float* Wn1l = Wn1 + (size_t)l * 320 * 256;
    const float* Wc1l = Wc1 + (size_t)l * 320 * 256;
    const float* We2l = We2 + (size_t)l * 64 * 64;
    const float* W1 = (n < 256) ? Wn1l : Wc1l;
    const int nn = n & 255;
    unsigned short* outp = wbig + ((((size_t)l * 32 + ntile) * 10 + ks) * 64 + lane) * 8;
    #pragma unroll
    for (int j = 0; j < 8; ++j) {
        int k = kbase + j;
        float val;
        if (k < 256) {
            val = W1[(size_t)k * 256 + nn];
        } else {
            int i = k - 256;
            float acc = 0.f;
            #pragma unroll 8
            for (int jj = 0; jj < 64; ++jj)
                acc += We2l[i * 64 + jj] * W1[(size_t)(256 + jj) * 256 + nn];
            val = acc;
        }
        outp[j] = f2bf(val);
    }
}

__global__ __launch_bounds__(64) void wn2_prep(
        const float* __restrict__ Wn2, unsigned short* __restrict__ wn2s)
{
    const int l = blockIdx.y;
    const int ntile = blockIdx.x / 8;
    const int ks = blockIdx.x % 8;
    const int lane = threadIdx.x;
    const int n = ntile * 16 + (lane & 15);
    const int kbase = ks * 32 + (lane >> 4) * 8;
    const float* Wn2l = Wn2 + (size_t)l * 256 * 128;
    unsigned short* outp = wn2s + ((((size_t)l * 8 + ntile) * 8 + ks) * 64 + lane) * 8;
    #pragma unroll
    for (int j = 0; j < 8; ++j)
        outp[j] = f2bf(Wn2l[(size_t)(kbase + j) * 128 + n]);
}

__global__ __launch_bounds__(512) void cep_prep(
        const float* __restrict__ be2,
        const float* __restrict__ Wn1, const float* __restrict__ Wc1,
        const float* __restrict__ bn1, const float* __restrict__ bc1,
        float* __restrict__ cep)
{
    const int l = blockIdx.x;
    const int j = threadIdx.x;
    const int jj = j & 255;
    const float* W1 = ((j < 256) ? Wn1 : Wc1) + (size_t)l * 320 * 256;
    const float* be2l = be2 + l * 64;
    float acc = (j < 256) ? bn1[l * 256 + jj] : bc1[l * 256 + jj];
    #pragma unroll 8
    for (int k = 0; k < 64; ++k)
        acc += be2l[k] * W1[(size_t)(256 + k) * 256 + jj];
    cep[l * 512 + j] = acc;
}

__global__ __launch_bounds__(256) void conv_kernel(
        const float* __restrict__ h, unsigned short* __restrict__ hbf)
{
    const int i = (blockIdx.x * 256 + threadIdx.x) * 4;
    float4 v = *(const float4*)(h + i);
    *(uint2*)(hbf + i) = make_uint2(pk_bf16(v.x, v.y), pk_bf16(v.z, v.w));
}

// ======================= fused edge kernel (sorted edges) ===================
// 64 edges/block, 512 threads (8 waves), ~77 KB LDS -> 2 blocks/CU.
// GEMM1 (operand-swapped: A=W-frag, B=edge-frag): wave w owns ntiles
//   {4w..4w+3} (cols 64w..64w+63), all 4 mtiles (64 edges).
//   C-layout: lane holds edge=mt*16+(lane&15), 4 consecutive weight-cols
//   q*4+i -> b64-packed bf16 LDS writes.
// waves 0-3 (cols 0:256): t_n -> s_t.  waves 4-7 (cols 256:512): coord
//   partial dot in registers -> 2 shuffles -> s_cw.
// Then: waves 0-1 segsum t_n (256 cols fp32) -> atomic Tbar[dst];
//       wave 2 finalizes cw -> x atomics.  No GEMM2 here.
// ---------------------------------------------------------------------------
__global__ __launch_bounds__(512, 4) void edge_kernel(
        const int* __restrict__ ssrc, const int* __restrict__ sdst,
        const float* __restrict__ sdist,
        const float* __restrict__ We1l, const float* __restrict__ be1l,
        const unsigned short* __restrict__ hbf,
        const unsigned short* __restrict__ wbig_l,
        const float* __restrict__ cep_l,
        const float* __restrict__ Wc2l,
        const float* __restrict__ x_in,
        float* __restrict__ Tbar, float* __restrict__ x_out)
{
    __shared__ __align__(16) unsigned short s_A[EPB][328];  // 320 + 8 pad
    __shared__ __align__(16) unsigned short s_t[EPB][264];  // 256 + 8 pad
    __shared__ __align__(16) float s_cw[EPB][4];
    __shared__ int s_src[EPB], s_dst[EPB];
    __shared__ unsigned long long s_mask;

    const int tid = threadIdx.x;
    const int eb = blockIdx.x * EPB;

    if (tid < EPB) {
        int dv = sdst[eb + tid];
        s_src[tid] = ssrc[eb + tid];
        s_dst[tid] = dv;
        int nxt = (tid == EPB - 1) ? -1 : sdst[eb + tid + 1];
        unsigned long long mk = __ballot(dv != nxt);
        if (tid == 0) s_mask = mk;
    }
    {   // s = silu(d*We1+be1) -> s_A[e][256..319]; 8 threads/edge, 8 cols each
        const int e = tid >> 3;
        const int j0 = (tid & 7) * 8;
        const float d = sdist[eb + e];
        unsigned tmp[4];
        #pragma unroll
        for (int j = 0; j < 4; ++j) {
            float a = silu_f(d * We1l[j0 + 2 * j] + be1l[j0 + 2 * j]);
            float b = silu_f(d * We1l[j0 + 2 * j + 1] + be1l[j0 + 2 * j + 1]);
            tmp[j] = pk_bf16(a, b);
        }
        *(bf16x8*)&s_A[e][j0 + 256] = *(const bf16x8*)tmp;
    }
    __syncthreads();   // s_src/s_dst ready for staging

    // ---- stage h rows: 2048 chunks of 16B, 4 per thread ----
    #pragma unroll
    for (int it = 0; it < 4; ++it) {
        const int c = tid + it * 512;
        const int row = c >> 5, ch = c & 31;
        const int node = (ch < 16) ? s_src[row] : s_dst[row];
        const int koff = (ch & 15) * 8;
        bf16x8 v = *(const bf16x8*)(hbf + (size_t)node * CD + koff);
        *(bf16x8*)&s_A[row][ch * 8] = v;
    }
    __syncthreads();

    const int wave = tid >> 6, lane = tid & 63;
    const int m = lane & 15, q = lane >> 4;

    // ---- GEMM1 (swapped operands) ----
    f32x4 acc[4][4];   // [nt][mt]
    #pragma unroll
    for (int nt = 0; nt < 4; ++nt)
        #pragma unroll
        for (int mt = 0; mt < 4; ++mt)
            acc[nt][mt] = (f32x4){0.f, 0.f, 0.f, 0.f};

    #pragma unroll
    for (int ks = 0; ks < 10; ++ks) {
        const int koff = ks * 32 + q * 8;
        bf16x8 ef[4];
        #pragma unroll
        for (int mt = 0; mt < 4; ++mt)
            ef[mt] = *(const bf16x8*)&s_A[mt * 16 + m][koff];
        #pragma unroll
        for (int nt = 0; nt < 4; ++nt) {
            bf16x8 wf = *(const bf16x8*)(wbig_l +
                ((size_t)((wave * 4 + nt) * 10 + ks) * 64 + lane) * 8);
            #pragma unroll
            for (int mt = 0; mt < 4; ++mt)
                acc[nt][mt] = __builtin_amdgcn_mfma_f32_16x16x32_bf16(wf, ef[mt], acc[nt][mt], 0, 0, 0);
        }
    }

    // ---- epilogue ----
    if (wave < 4) {
        // t_n: silu -> b64-packed bf16 into s_t[edge][col]
        #pragma unroll
        for (int nt = 0; nt < 4; ++nt) {
            const int c0 = (wave * 4 + nt) * 16 + q * 4;
            const float4 ce = *(const float4*)&cep_l[c0];
            #pragma unroll
            for (int mt = 0; mt < 4; ++mt) {
                float t0 = silu_f(acc[nt][mt][0] + ce.x);
                float t1 = silu_f(acc[nt][mt][1] + ce.y);
                float t2 = silu_f(acc[nt][mt][2] + ce.z);
                float t3 = silu_f(acc[nt][mt][3] + ce.w);
                *(uint2*)&s_t[mt * 16 + m][c0] =
                    make_uint2(pk_bf16(t0, t1), pk_bf16(t2, t3));
            }
        }
    } else {
        // coord half: in-register partial dot silu(pre)*Wc2
        float p[4] = {0.f, 0.f, 0.f, 0.f};
        #pragma unroll
        for (int nt = 0; nt < 4; ++nt) {
            const int c0 = (wave * 4 + nt) * 16 + q * 4;   // 256..511
            const float4 ce = *(const float4*)&cep_l[c0];
            const float4 wv = *(const float4*)&Wc2l[c0 - 256];
            #pragma unroll
            for (int mt = 0; mt < 4; ++mt) {
                p[mt] += silu_f(acc[nt][mt][0] + ce.x) * wv.x;
                p[mt] += silu_f(acc[nt][mt][1] + ce.y) * wv.y;
                p[mt] += silu_f(acc[nt][mt][2] + ce.z) * wv.z;
                p[mt] += silu_f(acc[nt][mt][3] + ce.w) * wv.w;
            }
        }
        #pragma unroll
        for (int mt = 0; mt < 4; ++mt) {
            p[mt] += __shfl_xor(p[mt], 16);
            p[mt] += __shfl_xor(p[mt], 32);
        }
        if (lane < 16) {
            #pragma unroll
            for (int mt = 0; mt < 4; ++mt)
                s_cw[mt * 16 + lane][wave - 4] = p[mt];
        }
    }
    __syncthreads();

    if (wave < 2) {
        // segsum of t_n over runs of equal dst -> atomic Tbar[dst*256+col]
        const unsigned long long mask = s_mask;
        const int colb = wave * 128 + lane * 2;
        float a0 = 0.f, a1 = 0.f;
        #pragma unroll 8
        for (int e = 0; e < EPB; ++e) {
            unsigned v = *(const unsigned*)&s_t[e][colb];
            a0 += bf2f((unsigned short)v);
            a1 += bf2f((unsigned short)(v >> 16));
            if ((mask >> e) & 1ull) {
                int dn = s_dst[e];
                atomicAdd(&Tbar[(size_t)dn * 256 + colb], a0);
                atomicAdd(&Tbar[(size_t)dn * 256 + colb + 1], a1);
                a0 = 0.f; a1 = 0.f;
            }
        }
    } else if (wave == 2) {
        // finalize coord weights, scatter x
        const int e = lane;
        float4 pv = *(const float4*)&s_cw[e][0];
        float cw = pv.x + pv.y + pv.z + pv.w;
        int sn = s_src[e], dn = s_dst[e];
        float dx0 = x_in[sn * 3 + 0] - x_in[dn * 3 + 0];
        float dx1 = x_in[sn * 3 + 1] - x_in[dn * 3 + 1];
        float dx2 = x_in[sn * 3 + 2] - x_in[dn * 3 + 2];
        atomicAdd(&x_out[dn * 3 + 0], cw * dx0);
        atomicAdd(&x_out[dn * 3 + 1], cw * dx1);
        atomicAdd(&x_out[dn * 3 + 2], cw * dx2);
    }
}

// ======================= node kernel: h += Tbar@Wn2 + deg*bn2 ===============
// 64 nodes/block, 256 threads (4 waves). wave w: ntiles {2w,2w+1}, 4 mtiles.
// Also emits the bf16 shadow of the updated h.
// ---------------------------------------------------------------------------
__global__ __launch_bounds__(256) void node_kernel(
        const float* __restrict__ Tbar, const int* __restrict__ deg,
        const unsigned short* __restrict__ wn2_l, const float* __restrict__ bn2l,
        float* __restrict__ h, unsigned short* __restrict__ hbf)
{
    const int nb = blockIdx.x * 64;
    const int tid = threadIdx.x;
    const int wave = tid >> 6, lane = tid & 63;
    const int m = lane & 15, q = lane >> 4;

    f32x4 acc[2][4];
    #pragma unroll
    for (int nt = 0; nt < 2; ++nt)
        #pragma unroll
        for (int mt = 0; mt < 4; ++mt)
            acc[nt][mt] = (f32x4){0.f, 0.f, 0.f, 0.f};

    #pragma unroll
    for (int ks = 0; ks < 8; ++ks) {
        bf16x8 af[4];
        #pragma unroll
        for (int mt = 0; mt < 4; ++mt) {
            const int node = nb + mt * 16 + m;
            if (node < NN) {
                const float* tp = Tbar + (size_t)node * 256 + ks * 32 + q * 8;
                float4 f0 = *(const float4*)tp;
                float4 f1 = *(const float4*)(tp + 4);
                unsigned u[4] = { pk_bf16(f0.x, f0.y), pk_bf16(f0.z, f0.w),
                                  pk_bf16(f1.x, f1.y), pk_bf16(f1.z, f1.w) };
                af[mt] = *(const bf16x8*)u;
            } else {
                af[mt] = (bf16x8){0,0,0,0,0,0,0,0};
            }
        }
        #pragma unroll
        for (int nt = 0; nt < 2; ++nt) {
            bf16x8 wf = *(const bf16x8*)(wn2_l +
                ((size_t)((wave * 2 + nt) * 8 + ks) * 64 + lane) * 8);
            #pragma unroll
            for (int mt = 0; mt < 4; ++mt)
                acc[nt][mt] = __builtin_amdgcn_mfma_f32_16x16x32_bf16(af[mt], wf, acc[nt][mt], 0, 0, 0);
        }
    }
    #pragma unroll
    for (int nt = 0; nt < 2; ++nt) {
        const int col = (wave * 2 + nt) * 16 + m;
        const float bb = bn2l[col];
        #pragma unroll
        for (int mt = 0; mt < 4; ++mt) {
            #pragma unroll
            for (int i = 0; i < 4; ++i) {
                const int node = nb + mt * 16 + q * 4 + i;
                if (node < NN) {
                    float val = acc[nt][mt][i] + (float)deg[node] * bb
                              + h[(size_t)node * CD + col];
                    h[(size_t)node * CD + col] = val;
                    hbf[(size_t)node * CD + col] = f2bf(val);
                }
            }
        }
    }
}

// ======================= final layernorm ====================================
__global__ __launch_bounds__(256) void final_kernel(
        const float* __restrict__ h, const float* __restrict__ x,
        const float* __restrict__ gamma, const float* __restrict__ beta,
        float* __restrict__ out)
{
    const int lane = threadIdx.x & 63;
    const int wave = threadIdx.x >> 6;
    const int n = blockIdx.x * 4 + wave;
    float v0 = h[(size_t)n * CD + lane];
    float v1 = h[(size_t)n * CD + 64 + lane];
    float ssum = v0 + v1;
    for (int off = 32; off; off >>= 1) ssum += __shfl_xor(ssum, off);
    float mu = ssum * (1.f / 128.f);
    float d0 = v0 - mu, d1 = v1 - mu;
    float sq = d0 * d0 + d1 * d1;
    for (int off = 32; off; off >>= 1) sq += __shfl_xor(sq, off);
    float rstd = rsqrtf(sq * (1.f / 128.f) + 1e-5f);
    out[(size_t)n * CD + lane]      = gamma[lane]      * d0 * rstd + beta[lane];
    out[(size_t)n * CD + 64 + lane] = gamma[64 + lane] * d1 * rstd + beta[64 + lane];
    if (threadIdx.x < 12) {
        int nn = blockIdx.x * 4 + threadIdx.x / 3;
        int c = threadIdx.x % 3;
        out[(size_t)NN * CD + nn * 3 + c] = x[nn * 3 + c];
    }
}

static inline size_t align_up(size_t v) { return (v + 255) & ~(size_t)255; }

extern "C" void kernel_launch(void* const* d_in, const int* in_sizes, int n_in,
                              void* d_out, int out_size, void* d_ws, size_t ws_size,
                              hipStream_t stream)
{
    const float* single = (const float*)d_in[0];
    const float* coords = (const float*)d_in[2];
    const int*   eidx   = (const int*)d_in[3];
    const float* edist  = (const float*)d_in[4];
    const float* We1 = (const float*)d_in[5];
    const float* be1 = (const float*)d_in[6];
    const float* We2 = (const float*)d_in[7];
    const float* be2 = (const float*)d_in[8];
    const float* Wn1 = (const float*)d_in[9];
    const float* bn1 = (const float*)d_in[10];
    const float* Wn2 = (const float*)d_in[11];
    const float* bn2 = (const float*)d_in[12];
    const float* Wc1 = (const float*)d_in[13];
    const float* bc1 = (const float*)d_in[14];
    const float* Wc2 = (const float*)d_in[15];
    const float* gamma = (const float*)d_in[16];
    const float* beta  = (const float*)d_in[17];
    float* out = (float*)d_out;

    char* w = (char*)d_ws;
    float* h0  = (float*)w;  w += align_up((size_t)NN * CD * 4);
    float* x0  = (float*)w;  w += align_up((size_t)NN * 3 * 4);
    float* x1  = (float*)w;  w += align_up((size_t)NN * 3 * 4);
    unsigned short* hbf  = (unsigned short*)w; w += align_up((size_t)NN * CD * 2);
    unsigned short* wbig = (unsigned short*)w; w += align_up((size_t)4 * 512 * 320 * 2);
    unsigned short* wn2s = (unsigned short*)w; w += align_up((size_t)4 * 256 * 128 * 2);
    float* cep = (float*)w;  w += align_up((size_t)4 * 512 * 4);
    int* hist   = (int*)w;   w += align_up((size_t)HBINS * 4);
    int* offs   = (int*)w;   w += align_up((size_t)HBINS * 4);
    int* cursor = (int*)w;   w += align_up((size_t)HBINS * 4);
    int* bsum   = (int*)w;   w += align_up((size_t)256 * 4);
    int* ssrc   = (int*)w;   w += align_up((size_t)NE * 4);
    int* sdst   = (int*)w;   w += align_up((size_t)NE * 4);
    float* sdist = (float*)w; w += align_up((size_t)NE * 4);
    float* Tbar = (float*)w; w += align_up((size_t)NN * 256 * 4);

    // ---- sort edges by dst (once; constant across layers) ----
    hipMemsetAsync(hist, 0, (size_t)HBINS * 4, stream);
    hist_kernel<<<(NE + 255) / 256, 256, 0, stream>>>(eidx + NE, hist);
    scan1_kernel<<<HBINS / 256, 256, 0, stream>>>(hist, offs, bsum);
    scan2_kernel<<<1, 256, 0, stream>>>(bsum);
    scan3_kernel<<<HBINS / 256, 256, 0, stream>>>(offs, bsum, cursor);
    scatter_kernel<<<(NE + 255) / 256, 256, 0, stream>>>(eidx, edist, cursor, ssrc, sdst, sdist);

    // ---- weight prep ----
    wbig_prep<<<dim3(320, 4), 64, 0, stream>>>(We2, Wn1, Wc1, wbig);
    wn2_prep<<<dim3(64, 4), 64, 0, stream>>>(Wn2, wn2s);
    cep_prep<<<4, 512, 0, stream>>>(be2, Wn1, Wc1, bn1, bc1, cep);

    hipMemcpyAsync(h0, single, (size_t)NN * CD * 4, hipMemcpyDeviceToDevice, stream);
    hipMemcpyAsync(x0, coords, (size_t)NN * 3 * 4, hipMemcpyDeviceToDevice, stream);
    conv_kernel<<<(NN * CD) / 1024, 256, 0, stream>>>(single, hbf);

    float* xc = x0; float* xn = x1;
    for (int l = 0; l < 4; ++l) {
        hipMemsetAsync(Tbar, 0, (size_t)NN * 256 * 4, stream);
        hipMemcpyAsync(xn, xc, (size_t)NN * 3 * 4, hipMemcpyDeviceToDevice, stream);
        edge_kernel<<<NE / EPB, 512, 0, stream>>>(
            ssrc, sdst, sdist,
            We1 + l * 64, be1 + l * 64,
            hbf,
            wbig + (size_t)l * 512 * 320,
            cep + l * 512,
            Wc2 + l * 256,
            xc, Tbar, xn);
        node_kernel<<<(NN + 63) / 64, 256, 0, stream>>>(
            Tbar, hist,
            wn2s + (size_t)l * 256 * 128,
            bn2 + l * CD, h0, hbf);
        float* t = xc; xc = xn; xn = t;
    }
    final_kernel<<<NN / 4, 256, 0, stream>>>(h0, xc, gamma, beta, out);
}